// Round 3
// baseline (389.848 us; speedup 1.0000x reference)
//
#include <hip/hip_runtime.h>
#include <hip/hip_cooperative_groups.h>

namespace cg = cooperative_groups;

// ---------------- problem constants ----------------
// N=512 nodes/heads, F_IN=256, H=64, C=64, K=12, ALPHA=0.2
// d_out: adj (512x512) followed by out (512x64), float32

// ---------------- ws float offsets ----------------
#define CAND_OFF  0           // 512*12 float2 = 12288 floats (val, idx-bits)
#define W2_OFF    12288       // 512*256 : w2[h][f]
#define E2P_OFF   143360      // 4*512*512 : E2 f-quarter partials [q][h][j]
#define PART_OFF  143360      // 128*768 overlays E2P (E2P dead before P6)
#define MIDC_OFF  1191936     // 12*32768 : compact mid rows

// header indices in shdr (block-local LDS, redundant per block)
#define H_M    0
#define H_R    1
#define H_ROWS 2
#define H_ER   14
#define H_EJ   26
#define H_ECJ  38

// smem scratch layout (floats)
#define S_XET  0       // 3072  (P3)
#define S_WHP  3072    // 3072  (P3, P6)
#define S_W1   6144    // 256   (P3)
#define S_W2   6400    // 256   (P3)
#define S_AS   0       // 4352  (P4)
#define S_BS   4352    // 4352  (P4)
#define S_E2S  0       // 512   (P5)
#define S_MIDT 0       // 3072  (P6)

__device__ __forceinline__ float leaky_(float x) { return fmaxf(x, 0.2f * x); }
__device__ __forceinline__ float elu_(float x)   { return x > 0.f ? x : __expf(x) - 1.f; }

__global__ __launch_bounds__(256, 4) void mega(
    const float* __restrict__ X, const float* __restrict__ Wst,
    const float* __restrict__ ast, const float* __restrict__ Wout,
    const float* __restrict__ aout, const float* __restrict__ V,
    float* __restrict__ wsf, float* __restrict__ out) {
  cg::grid_group grid = cg::this_grid();
  __shared__ __align__(16) float smem[8704];   // 34816 B scratch union
  __shared__ int   shdr[64];                   // persistent header
  __shared__ float kth_s;
  __shared__ float e1r[12];                    // persistent e1 (this head)
  __shared__ float whl[768];                   // persistent Wh at entry cols (this head)
  __shared__ float redv[4]; __shared__ int redi[4];
  __shared__ float candv[12]; __shared__ int candi[12];
  __shared__ int   es_s[12];
  __shared__ float redf[48];
  __shared__ float mr12[12], sr12[12], av12[12];

  int b = blockIdx.x, t = threadIdx.x, l = t & 63, w = t >> 6;

  // ========== P1: A row b = V[b]·V^T, write raw A, per-block top-12, zero out ==========
  {
    if (t < 64) smem[t] = V[b * 64 + t];
    __syncthreads();
    float vr0, vr1;
    {
      const float4* vj = reinterpret_cast<const float4*>(V + t * 64);
      float acc = 0.f;
      #pragma unroll
      for (int q = 0; q < 16; ++q) {
        float4 v4 = vj[q];
        acc += v4.x * smem[q*4] + v4.y * smem[q*4+1] + v4.z * smem[q*4+2] + v4.w * smem[q*4+3];
      }
      vr0 = acc;
    }
    {
      const float4* vj = reinterpret_cast<const float4*>(V + (t + 256) * 64);
      float acc = 0.f;
      #pragma unroll
      for (int q = 0; q < 16; ++q) {
        float4 v4 = vj[q];
        acc += v4.x * smem[q*4] + v4.y * smem[q*4+1] + v4.z * smem[q*4+2] + v4.w * smem[q*4+3];
      }
      vr1 = acc;
    }
    out[b * 512 + t]       = vr0;
    out[b * 512 + 256 + t] = vr1;

    float v0 = vr0, v1 = vr1;
    int j0 = t, j1 = t + 256;
    for (int round = 0; round < 12; ++round) {
      float m; int mi;
      if (v0 >= v1) { m = v0; mi = j0; } else { m = v1; mi = j1; }
      #pragma unroll
      for (int d = 1; d < 64; d <<= 1) {
        float ov = __shfl_xor(m, d);
        int   oi = __shfl_xor(mi, d);
        if (ov > m || (ov == m && oi < mi)) { m = ov; mi = oi; }
      }
      if (l == 0) { redv[w] = m; redi[w] = mi; }
      __syncthreads();
      float bm = redv[0]; int bi = redi[0];
      #pragma unroll
      for (int ww = 1; ww < 4; ++ww)
        if (redv[ww] > bm || (redv[ww] == bm && redi[ww] < bi)) { bm = redv[ww]; bi = redi[ww]; }
      if (t == 0) { candv[round] = bm; candi[round] = bi; }
      if (bi == j0) v0 = -INFINITY;
      if (bi == j1) v1 = -INFINITY;
      __syncthreads();
    }
    if (t < 12) {
      float2 c; c.x = candv[t]; c.y = __int_as_float(b * 512 + candi[t]);
      *reinterpret_cast<float2*>(wsf + CAND_OFF + (b * 12 + t) * 2) = c;
    }
    if (b < 128) out[262144 + b * 256 + t] = 0.f;
  }
  grid.sync();  // ---- sync 1 ----

  // ========== P2: every block redundantly reduces 6144 candidates -> top-12 + header ==========
  {
    float lv[12]; int li[12];
    #pragma unroll
    for (int q = 0; q < 12; ++q) { lv[q] = -INFINITY; li[q] = 0x7FFFFFFF; }
    const float2* cp = reinterpret_cast<const float2*>(wsf + CAND_OFF);
    for (int k = 0; k < 24; ++k) {
      float2 c = cp[t * 24 + k];
      float cv = c.x; int ci2 = __float_as_int(c.y);
      if (cv > lv[11] || (cv == lv[11] && ci2 < li[11])) {
        #pragma unroll
        for (int q = 0; q < 12; ++q) {
          bool sw = (cv > lv[q]) || (cv == lv[q] && ci2 < li[q]);
          if (sw) { float tv = lv[q]; int ti = li[q]; lv[q] = cv; li[q] = ci2; cv = tv; ci2 = ti; }
        }
      }
    }
    for (int round = 0; round < 12; ++round) {
      float m = lv[0]; int mi = li[0];
      #pragma unroll
      for (int d = 1; d < 64; d <<= 1) {
        float ov = __shfl_xor(m, d);
        int   oi = __shfl_xor(mi, d);
        if (ov > m || (ov == m && oi < mi)) { m = ov; mi = oi; }
      }
      if (l == 0) { redv[w] = m; redi[w] = mi; }
      __syncthreads();
      float bm = redv[0]; int bi = redi[0];
      #pragma unroll
      for (int ww = 1; ww < 4; ++ww)
        if (redv[ww] > bm || (redv[ww] == bm && redi[ww] < bi)) { bm = redv[ww]; bi = redi[ww]; }
      if (t == 0) { candv[round] = bm; candi[round] = bi; }
      if (li[0] == bi) {
        #pragma unroll
        for (int q = 0; q < 11; ++q) { lv[q] = lv[q + 1]; li[q] = li[q + 1]; }
        lv[11] = -INFINITY; li[11] = 0x7FFFFFFF;
      }
      __syncthreads();
    }
    if (t == 0) {
      float kv = candv[11];
      kth_s = kv;
      int M = 0;
      for (int q = 0; q < 12; ++q) {
        if (candv[q] > kv) {
          int ix = candi[q];
          int p = M++;
          while (p > 0 && es_s[p - 1] > ix) { es_s[p] = es_s[p - 1]; --p; }
          es_s[p] = ix;
        }
      }
      int R = 0;
      for (int m2 = 0; m2 < M; ++m2) {
        int i2 = es_s[m2] >> 9, j2 = es_s[m2] & 511;
        if (R == 0 || shdr[H_ROWS + R - 1] != i2) { shdr[H_ROWS + R] = i2; ++R; }
        shdr[H_ER + m2] = R - 1;
        shdr[H_EJ + m2] = j2;
      }
      shdr[H_M] = M; shdr[H_R] = R;
      for (int m2 = 0; m2 < M; ++m2) {
        int cj = -1;
        for (int r = 0; r < R; ++r) if (shdr[H_ROWS + r] == shdr[H_EJ + m2]) cj = r;
        shdr[H_ECJ + m2] = cj;
      }
      for (int m2 = M; m2 < 12; ++m2) { shdr[H_ER + m2] = 0; shdr[H_EJ + m2] = 0; shdr[H_ECJ + m2] = -1; }
      for (int r = R; r < 12; ++r) shdr[H_ROWS + r] = 0;
    }
    __syncthreads();
  }

  // ========== P3a: adj row b = (A > kth), in place ==========
  {
    float kv = kth_s;
    float a0 = out[b * 512 + t], a1 = out[b * 512 + 256 + t];
    out[b * 512 + t]       = (a0 > kv) ? 1.f : 0.f;
    out[b * 512 + 256 + t] = (a1 > kv) ? 1.f : 0.f;
  }

  // ========== P3b: head pass (h = b): W read once -> w1/w2, Wh@entries, e1 ==========
  {
    int M = shdr[H_M], R = shdr[H_R];
    #pragma unroll
    for (int m = 0; m < 12; ++m) {
      float v = 0.f;
      if (m < M) v = X[shdr[H_EJ + m] * 256 + t];
      smem[S_XET + t * 12 + m] = v;
    }
    __syncthreads();

    const float* Wb = Wst + b * 16384;
    int fg = l >> 4, kc = (l & 15) << 2;
    float4 a1q = *reinterpret_cast<const float4*>(ast + b * 128 + kc);
    float4 a2q = *reinterpret_cast<const float4*>(ast + b * 128 + 64 + kc);
    float wh[12][4];
    #pragma unroll
    for (int m = 0; m < 12; ++m) { wh[m][0] = wh[m][1] = wh[m][2] = wh[m][3] = 0.f; }

    #pragma unroll 4
    for (int it = 0; it < 16; ++it) {
      int f = w * 64 + it * 4 + fg;
      float4 wq = *reinterpret_cast<const float4*>(Wb + f * 64 + kc);
      float p1 = wq.x*a1q.x + wq.y*a1q.y + wq.z*a1q.z + wq.w*a1q.w;
      float p2 = wq.x*a2q.x + wq.y*a2q.y + wq.z*a2q.z + wq.w*a2q.w;
      #pragma unroll
      for (int d = 1; d < 16; d <<= 1) { p1 += __shfl_xor(p1, d); p2 += __shfl_xor(p2, d); }
      if ((l & 15) == 0) { smem[S_W1 + f] = p1; smem[S_W2 + f] = p2; }
      const float4* xr = reinterpret_cast<const float4*>(&smem[S_XET + f * 12]);
      float4 xa = xr[0], xb = xr[1], xc = xr[2];
      float xv[12] = { xa.x, xa.y, xa.z, xa.w, xb.x, xb.y, xb.z, xb.w,
                       xc.x, xc.y, xc.z, xc.w };
      #pragma unroll
      for (int m = 0; m < 12; ++m) {
        wh[m][0] += xv[m] * wq.x;
        wh[m][1] += xv[m] * wq.y;
        wh[m][2] += xv[m] * wq.z;
        wh[m][3] += xv[m] * wq.w;
      }
    }
    #pragma unroll
    for (int m = 0; m < 12; ++m) {
      #pragma unroll
      for (int q = 0; q < 4; ++q) {
        float x = wh[m][q];
        x += __shfl_xor(x, 16);
        x += __shfl_xor(x, 32);
        wh[m][q] = x;
      }
    }
    if (l < 16) {
      #pragma unroll
      for (int m = 0; m < 12; ++m) {
        float4 vv = make_float4(wh[m][0], wh[m][1], wh[m][2], wh[m][3]);
        *reinterpret_cast<float4*>(&smem[S_WHP + w * 768 + m * 64 + kc]) = vv;
      }
    }
    __syncthreads();
    #pragma unroll
    for (int c = 0; c < 3; ++c) {
      int o = c * 256 + t;
      whl[o] = smem[S_WHP + o] + smem[S_WHP + 768 + o] + smem[S_WHP + 1536 + o] + smem[S_WHP + 2304 + o];
    }
    wsf[W2_OFF + b * 256 + t] = smem[S_W2 + t];
    for (int r = w; r < R; r += 4) {
      int row = shdr[H_ROWS + r];
      float p = 0.f;
      #pragma unroll
      for (int s = 0; s < 4; ++s) {
        int f = s * 64 + l;
        p += X[row * 256 + f] * smem[S_W1 + f];
      }
      #pragma unroll
      for (int d = 1; d < 64; d <<= 1) p += __shfl_xor(p, d);
      if (l == 0) e1r[r] = p;
    }
  }
  grid.sync();  // ---- sync 2 ----

  // ========== P4: E2 = W2 · X^T as 4 f-quarter partials (blocks 0..255) ==========
  if (b < 256) {
    int q = b >> 6, bh = (b >> 3) & 7, bj = b & 7;
    int r = t >> 2, c0 = (t & 3) * 16;
    const float* wsrc = wsf + W2_OFF + (bh * 64 + r) * 256 + q * 64 + c0;
    const float* xsrc = X + (bj * 64 + r) * 256 + q * 64 + c0;
    #pragma unroll
    for (int u = 0; u < 4; ++u) {
      float4 a4 = *reinterpret_cast<const float4*>(wsrc + u * 4);
      float4 b4 = *reinterpret_cast<const float4*>(xsrc + u * 4);
      smem[S_AS + (c0 + u*4 + 0) * 68 + r] = a4.x; smem[S_AS + (c0 + u*4 + 1) * 68 + r] = a4.y;
      smem[S_AS + (c0 + u*4 + 2) * 68 + r] = a4.z; smem[S_AS + (c0 + u*4 + 3) * 68 + r] = a4.w;
      smem[S_BS + (c0 + u*4 + 0) * 68 + r] = b4.x; smem[S_BS + (c0 + u*4 + 1) * 68 + r] = b4.y;
      smem[S_BS + (c0 + u*4 + 2) * 68 + r] = b4.z; smem[S_BS + (c0 + u*4 + 3) * 68 + r] = b4.w;
    }
    __syncthreads();
    int th = t >> 4, tj = t & 15;
    float acc[4][4] = {};
    #pragma unroll 8
    for (int f = 0; f < 64; ++f) {
      float4 a4 = *reinterpret_cast<const float4*>(&smem[S_AS + f * 68 + th * 4]);
      float4 b4 = *reinterpret_cast<const float4*>(&smem[S_BS + f * 68 + tj * 4]);
      float av[4] = { a4.x, a4.y, a4.z, a4.w };
      float bv[4] = { b4.x, b4.y, b4.z, b4.w };
      #pragma unroll
      for (int i = 0; i < 4; ++i)
        #pragma unroll
        for (int j = 0; j < 4; ++j)
          acc[i][j] += av[i] * bv[j];
    }
    float* dst = wsf + E2P_OFF + q * 262144 + (bh * 64 + th * 4) * 512 + bj * 64 + tj * 4;
    #pragma unroll
    for (int i = 0; i < 4; ++i) {
      float4 o4 = make_float4(acc[i][0], acc[i][1], acc[i][2], acc[i][3]);
      *reinterpret_cast<float4*>(dst + i * 512) = o4;
    }
  }
  grid.sync();  // ---- sync 3 ----

  // ========== P5: per-head softmax stats + mid accumulate (head b) ==========
  {
    int M = shdr[H_M], R = shdr[H_R];
    {
      float s0 = 0.f, s1 = 0.f;
      #pragma unroll
      for (int qq = 0; qq < 4; ++qq) {
        s0 += wsf[E2P_OFF + qq * 262144 + b * 512 + t];
        s1 += wsf[E2P_OFF + qq * 262144 + b * 512 + 256 + t];
      }
      smem[S_E2S + t] = s0; smem[S_E2S + 256 + t] = s1;
    }
    __syncthreads();
    {
      float p = fmaxf(smem[S_E2S + w * 128 + l], smem[S_E2S + w * 128 + 64 + l]);
      #pragma unroll
      for (int d = 1; d < 64; d <<= 1) p = fmaxf(p, __shfl_xor(p, d));
      if (l == 0) redv[w] = p;
    }
    __syncthreads();
    float maxe2 = fmaxf(fmaxf(redv[0], redv[1]), fmaxf(redv[2], redv[3]));
    for (int r = 0; r < R; ++r) {
      float e1_ = e1r[r];
      float m_ = leaky_(e1_ + maxe2);
      float pe = __expf(leaky_(e1_ + smem[S_E2S + t]) - m_) +
                 __expf(leaky_(e1_ + smem[S_E2S + 256 + t]) - m_);
      #pragma unroll
      for (int d = 1; d < 64; d <<= 1) pe += __shfl_xor(pe, d);
      if (l == 0) redf[r * 4 + w] = pe;
      if (t == r) mr12[r] = m_;
    }
    __syncthreads();
    if (t < R) sr12[t] = redf[t * 4] + redf[t * 4 + 1] + redf[t * 4 + 2] + redf[t * 4 + 3];
    __syncthreads();
    if (t < M) {
      int r = shdr[H_ER + t];
      av12[t] = __expf(leaky_(e1r[r] + smem[S_E2S + shdr[H_EJ + t]]) - mr12[r]) / sr12[r];
    }
    __syncthreads();
    for (int r = w; r < R; r += 4) {
      float a = 0.f;
      #pragma unroll
      for (int m = 0; m < 12; ++m) {
        if (m < M && shdr[H_ER + m] == r) a += av12[m] * whl[m * 64 + l];
      }
      wsf[MIDC_OFF + r * 32768 + b * 64 + l] = elu_(a);
    }
  }
  grid.sync();  // ---- sync 4 ----

  // ========== P6: Wh2 partials over 256-col chunks (blocks 0..127) ==========
  if (b < 128) {
    int R = shdr[H_R];
    #pragma unroll
    for (int m = 0; m < 12; ++m) {
      float v = 0.f;
      if (m < R) v = wsf[MIDC_OFF + m * 32768 + b * 256 + t];
      smem[S_MIDT + t * 12 + m] = v;
    }
    __syncthreads();
    float acc[12];
    #pragma unroll
    for (int m = 0; m < 12; ++m) acc[m] = 0.f;
    #pragma unroll 2
    for (int ci = 0; ci < 64; ++ci) {
      int cc = w * 64 + ci;
      float wv = Wout[(b * 256 + cc) * 64 + l];
      const float4* xr = reinterpret_cast<const float4*>(&smem[S_MIDT + cc * 12]);
      float4 xa = xr[0], xb = xr[1], xc = xr[2];
      acc[0] += xa.x * wv; acc[1] += xa.y * wv; acc[2]  += xa.z * wv; acc[3]  += xa.w * wv;
      acc[4] += xb.x * wv; acc[5] += xb.y * wv; acc[6]  += xb.z * wv; acc[7]  += xb.w * wv;
      acc[8] += xc.x * wv; acc[9] += xc.y * wv; acc[10] += xc.z * wv; acc[11] += xc.w * wv;
    }
    #pragma unroll
    for (int m = 0; m < 12; ++m) smem[S_WHP + w * 768 + m * 64 + l] = acc[m];
    __syncthreads();
    #pragma unroll
    for (int c = 0; c < 3; ++c) {
      int o = c * 256 + t;
      float s = smem[S_WHP + o] + smem[S_WHP + 768 + o] + smem[S_WHP + 1536 + o] + smem[S_WHP + 2304 + o];
      wsf[PART_OFF + b * 768 + o] = s;
    }
  }
  grid.sync();  // ---- sync 5 ----

  // ========== P7: block 0: reduce partials, layer-2 softmax, final output ==========
  if (b == 0) {
    int M = shdr[H_M], R = shdr[H_R];
    #pragma unroll
    for (int c = 0; c < 3; ++c) {
      int o = c * 256 + t;
      float s = 0.f;
      #pragma unroll 8
      for (int bb = 0; bb < 128; ++bb) s += wsf[PART_OFF + bb * 768 + o];
      whl[o] = s;   // Wh2
    }
    __syncthreads();
    if (t < R) {
      float s1 = 0.f, s2 = 0.f;
      for (int k = 0; k < 64; ++k) {
        float wv = whl[t * 64 + k];
        s1 += wv * aout[k];
        s2 += wv * aout[64 + k];
      }
      candv[t] = s1;   // e1o
      redf[t]  = s2;   // e2o
    }
    __syncthreads();
    if (t < R) {
      float maxe = 0.f;  // includes (512-R) implicit zeros
      for (int r = 0; r < R; ++r) maxe = fmaxf(maxe, redf[r]);
      float m_ = leaky_(candv[t] + maxe);
      float s = (float)(512 - R) * __expf(leaky_(candv[t]) - m_);
      for (int r = 0; r < R; ++r) s += __expf(leaky_(candv[t] + redf[r]) - m_);
      mr12[t] = m_; sr12[t] = s;
    }
    __syncthreads();
    if (t < M) {
      int r  = shdr[H_ER + t];
      int cj = shdr[H_ECJ + t];
      float e2v = (cj >= 0) ? redf[cj] : 0.f;
      av12[t] = __expf(leaky_(candv[r] + e2v) - mr12[r]) / sr12[r];
    }
    __syncthreads();
    for (int r = w; r < R; r += 4) {
      float a = 0.f;
      #pragma unroll
      for (int m = 0; m < 12; ++m) {
        if (m < M && shdr[H_ER + m] == r) {
          int cj = shdr[H_ECJ + m];
          float wv = (cj >= 0) ? whl[cj * 64 + l] : 0.f;
          a += av12[m] * wv;
        }
      }
      int row = shdr[H_ROWS + r];
      float o2 = elu_(a);
      out[262144 + row * 64 + l] = elu_(V[row * 64 + l] * o2);
    }
  }
}

extern "C" void kernel_launch(void* const* d_in, const int* in_sizes, int n_in,
                              void* d_out, int out_size, void* d_ws, size_t ws_size,
                              hipStream_t stream) {
  const float* X    = (const float*)d_in[0];
  const float* Wst  = (const float*)d_in[1];
  const float* ast  = (const float*)d_in[2];
  const float* Wout = (const float*)d_in[3];
  const float* aout = (const float*)d_in[4];
  const float* V    = (const float*)d_in[5];
  float* out = (float*)d_out;
  float* wsf = (float*)d_ws;

  void* args[] = { (void*)&X, (void*)&Wst, (void*)&ast, (void*)&Wout,
                   (void*)&aout, (void*)&V, (void*)&wsf, (void*)&out };
  hipLaunchCooperativeKernel((const void*)mega, dim3(512), dim3(256),
                             args, 0, stream);
}

// Round 4
// 165.042 us; speedup vs baseline: 2.3621x; 2.3621x over previous
//
#include <hip/hip_runtime.h>

// ---------------- problem constants ----------------
// N=512 nodes/heads, F_IN=256, H=64, C=64, K=12, ALPHA=0.2
// d_out: adj (512x512) followed by out (512x64), float32

// ---------------- ws float offsets ----------------
#define CAND_OFF 0        // 512*12 float2 = 12288 floats (val, idx-bits)
#define XT_OFF   12288    // 131072 : X^T [256][512]
#define KTH_OFF  143360   // 1 (padded to 64)
#define INT_OFF  143424   // 64 int slots (header)
#define MIDC_OFF 143488   // 12*32768 : compact mid rows
#define PART_OFF 536704   // 128*768  : Wh2 partials [block][o]

// header int indices
#define H_M    0
#define H_R    1
#define H_ROWS 2
#define H_ER   14
#define H_EJ   26
#define H_ECJ  38

__device__ __forceinline__ float leaky_(float x) { return fmaxf(x, 0.2f * x); }
__device__ __forceinline__ float elu_(float x)   { return x > 0.f ? x : __expf(x) - 1.f; }

// K1: blocks 0..511: A row b = V[b]·V^T -> d_out, per-row top-12 candidates,
//     zero out-section (b<128). Blocks 512..543: X^T 64x64 tile transpose.
__global__ __launch_bounds__(256) void k1_prep(const float* __restrict__ V,
                                               const float* __restrict__ X,
                                               float* __restrict__ wsf,
                                               float* __restrict__ out) {
  int b = blockIdx.x, t = threadIdx.x, l = t & 63, w = t >> 6;
  if (b < 512) {
    __shared__ float vi[64];
    __shared__ float redv[4]; __shared__ int redi[4];
    __shared__ float candv[12]; __shared__ int candi[12];
    if (t < 64) vi[t] = V[b * 64 + t];
    __syncthreads();
    float vr0, vr1;
    {
      const float4* vj = reinterpret_cast<const float4*>(V + t * 64);
      float acc = 0.f;
      #pragma unroll
      for (int q = 0; q < 16; ++q) {
        float4 v4 = vj[q];
        acc += v4.x * vi[q*4] + v4.y * vi[q*4+1] + v4.z * vi[q*4+2] + v4.w * vi[q*4+3];
      }
      vr0 = acc;
    }
    {
      const float4* vj = reinterpret_cast<const float4*>(V + (t + 256) * 64);
      float acc = 0.f;
      #pragma unroll
      for (int q = 0; q < 16; ++q) {
        float4 v4 = vj[q];
        acc += v4.x * vi[q*4] + v4.y * vi[q*4+1] + v4.z * vi[q*4+2] + v4.w * vi[q*4+3];
      }
      vr1 = acc;
    }
    out[b * 512 + t]       = vr0;
    out[b * 512 + 256 + t] = vr1;
    if (b < 128) out[262144 + b * 256 + t] = 0.f;

    float v0 = vr0, v1 = vr1;
    int j0 = t, j1 = t + 256;
    for (int round = 0; round < 12; ++round) {
      float m; int mi;
      if (v0 >= v1) { m = v0; mi = j0; } else { m = v1; mi = j1; }
      #pragma unroll
      for (int d = 1; d < 64; d <<= 1) {
        float ov = __shfl_xor(m, d);
        int   oi = __shfl_xor(mi, d);
        if (ov > m || (ov == m && oi < mi)) { m = ov; mi = oi; }
      }
      if (l == 0) { redv[w] = m; redi[w] = mi; }
      __syncthreads();
      float bm = redv[0]; int bi = redi[0];
      #pragma unroll
      for (int ww = 1; ww < 4; ++ww)
        if (redv[ww] > bm || (redv[ww] == bm && redi[ww] < bi)) { bm = redv[ww]; bi = redi[ww]; }
      if (t == 0) { candv[round] = bm; candi[round] = bi; }
      if (bi == j0) v0 = -INFINITY;
      if (bi == j1) v1 = -INFINITY;
      __syncthreads();
    }
    if (t < 12) {
      float2 c; c.x = candv[t]; c.y = __int_as_float(b * 512 + candi[t]);
      *reinterpret_cast<float2*>(wsf + CAND_OFF + (b * 12 + t) * 2) = c;
    }
  } else {
    __shared__ float tile[64][65];
    int ti = b - 512;          // 0..31
    int tjj = ti & 7;          // j-tile
    int tff = ti >> 3;         // f-tile
    int r = t >> 2, c0 = (t & 3) * 16;
    #pragma unroll
    for (int u = 0; u < 4; ++u) {
      float4 x4 = *reinterpret_cast<const float4*>(X + (tjj*64 + r)*256 + tff*64 + c0 + u*4);
      tile[c0+u*4+0][r] = x4.x; tile[c0+u*4+1][r] = x4.y;
      tile[c0+u*4+2][r] = x4.z; tile[c0+u*4+3][r] = x4.w;
    }
    __syncthreads();
    int fl = t >> 2, jc0 = (t & 3) * 16;
    #pragma unroll
    for (int u = 0; u < 4; ++u) {
      float4 o4 = make_float4(tile[fl][jc0+u*4+0], tile[fl][jc0+u*4+1],
                              tile[fl][jc0+u*4+2], tile[fl][jc0+u*4+3]);
      *reinterpret_cast<float4*>(wsf + XT_OFF + (tff*64 + fl)*512 + tjj*64 + jc0 + u*4) = o4;
    }
  }
}

// K2: single block: 6144 candidates -> global top-12 -> kth + header
__global__ void k2_header(float* __restrict__ wsf) {
  __shared__ float redv[4]; __shared__ int redi[4];
  __shared__ float candv[12]; __shared__ int candi[12];
  int t = threadIdx.x, l = t & 63, w = t >> 6;
  float lv[12]; int li[12];
  #pragma unroll
  for (int q = 0; q < 12; ++q) { lv[q] = -INFINITY; li[q] = 0x7FFFFFFF; }
  const float2* cp = reinterpret_cast<const float2*>(wsf + CAND_OFF);
  for (int k = 0; k < 24; ++k) {
    float2 c = cp[t * 24 + k];
    float cv = c.x; int ci2 = __float_as_int(c.y);
    if (cv > lv[11] || (cv == lv[11] && ci2 < li[11])) {
      #pragma unroll
      for (int q = 0; q < 12; ++q) {
        bool sw = (cv > lv[q]) || (cv == lv[q] && ci2 < li[q]);
        if (sw) { float tv = lv[q]; int ti = li[q]; lv[q] = cv; li[q] = ci2; cv = tv; ci2 = ti; }
      }
    }
  }
  for (int round = 0; round < 12; ++round) {
    float m = lv[0]; int mi = li[0];
    #pragma unroll
    for (int d = 1; d < 64; d <<= 1) {
      float ov = __shfl_xor(m, d);
      int   oi = __shfl_xor(mi, d);
      if (ov > m || (ov == m && oi < mi)) { m = ov; mi = oi; }
    }
    if (l == 0) { redv[w] = m; redi[w] = mi; }
    __syncthreads();
    float bm = redv[0]; int bi = redi[0];
    #pragma unroll
    for (int ww = 1; ww < 4; ++ww)
      if (redv[ww] > bm || (redv[ww] == bm && redi[ww] < bi)) { bm = redv[ww]; bi = redi[ww]; }
    if (t == 0) { candv[round] = bm; candi[round] = bi; }
    if (li[0] == bi) {
      #pragma unroll
      for (int q = 0; q < 11; ++q) { lv[q] = lv[q + 1]; li[q] = li[q + 1]; }
      lv[11] = -INFINITY; li[11] = 0x7FFFFFFF;
    }
    __syncthreads();
  }
  if (t == 0) {
    float kv = candv[11];
    int es[12];
    int M = 0;
    for (int q = 0; q < 12; ++q) {
      if (candv[q] > kv) {
        int ix = candi[q];
        int p = M++;
        while (p > 0 && es[p - 1] > ix) { es[p] = es[p - 1]; --p; }
        es[p] = ix;
      }
    }
    int rows[12], er_[12], ej_[12];
    int R = 0;
    for (int m2 = 0; m2 < M; ++m2) {
      int i2 = es[m2] >> 9, j2 = es[m2] & 511;
      if (R == 0 || rows[R - 1] != i2) rows[R++] = i2;
      er_[m2] = R - 1; ej_[m2] = j2;
    }
    int* ip = (int*)(wsf + INT_OFF);
    ip[H_M] = M; ip[H_R] = R;
    for (int r = 0; r < 12; ++r) ip[H_ROWS + r] = (r < R) ? rows[r] : 0;
    for (int m2 = 0; m2 < 12; ++m2) {
      ip[H_ER + m2] = (m2 < M) ? er_[m2] : 0;
      ip[H_EJ + m2] = (m2 < M) ? ej_[m2] : 0;
      int cj = -1;
      if (m2 < M) { for (int r = 0; r < R; ++r) if (rows[r] == ej_[m2]) cj = r; }
      ip[H_ECJ + m2] = cj;
    }
    wsf[KTH_OFF] = kv;
  }
}

// K3: one block per head h=b. adj row write; W read ONCE -> w1/w2, Wh@entries,
// e1; e2 matvec over L2-resident X^T; softmax stats; mid_c write.
__global__ __launch_bounds__(256) void k3_heads(
    const float* __restrict__ X, const float* __restrict__ Wst,
    const float* __restrict__ ast, float* __restrict__ wsf,
    float* __restrict__ out) {
  __shared__ int   shdr[64];
  __shared__ __align__(16) float XeT[3072];   // [f][m]
  __shared__ __align__(16) float whp[3072];
  __shared__ float w1l[256], w2l[256];
  __shared__ float e2s[512];
  __shared__ float whl[768];
  __shared__ float e1r[12], mr12[12], sr12[12], av12[12];
  __shared__ float redv[4], redf[48];

  int b = blockIdx.x, t = threadIdx.x, l = t & 63, w = t >> 6;
  const int* ip = (const int*)(wsf + INT_OFF);

  // adj row write (independent of header)
  {
    float kv = wsf[KTH_OFF];
    float a0 = out[b * 512 + t], a1 = out[b * 512 + 256 + t];
    out[b * 512 + t]       = (a0 > kv) ? 1.f : 0.f;
    out[b * 512 + 256 + t] = (a1 > kv) ? 1.f : 0.f;
  }
  if (t < 50) shdr[t] = ip[t];
  __syncthreads();
  int M = shdr[H_M], R = shdr[H_R];

  #pragma unroll
  for (int m = 0; m < 12; ++m) {
    float v = 0.f;
    if (m < M) v = X[shdr[H_EJ + m] * 256 + t];
    XeT[t * 12 + m] = v;
  }
  __syncthreads();

  // W pass: W_h read once; w1/w2 (k-reduce) + Wh@entries (f-reduce partials)
  const float* Wb = Wst + b * 16384;
  int fg = l >> 4, kc = (l & 15) << 2;
  float4 a1q = *reinterpret_cast<const float4*>(ast + b * 128 + kc);
  float4 a2q = *reinterpret_cast<const float4*>(ast + b * 128 + 64 + kc);
  float wh[12][4];
  #pragma unroll
  for (int m = 0; m < 12; ++m) { wh[m][0] = wh[m][1] = wh[m][2] = wh[m][3] = 0.f; }

  #pragma unroll 4
  for (int it = 0; it < 16; ++it) {
    int f = w * 64 + it * 4 + fg;
    float4 wq = *reinterpret_cast<const float4*>(Wb + f * 64 + kc);
    float p1 = wq.x*a1q.x + wq.y*a1q.y + wq.z*a1q.z + wq.w*a1q.w;
    float p2 = wq.x*a2q.x + wq.y*a2q.y + wq.z*a2q.z + wq.w*a2q.w;
    #pragma unroll
    for (int d = 1; d < 16; d <<= 1) { p1 += __shfl_xor(p1, d); p2 += __shfl_xor(p2, d); }
    if ((l & 15) == 0) { w1l[f] = p1; w2l[f] = p2; }
    const float4* xr = reinterpret_cast<const float4*>(&XeT[f * 12]);
    float4 xa = xr[0], xb = xr[1], xc = xr[2];
    float xv[12] = { xa.x, xa.y, xa.z, xa.w, xb.x, xb.y, xb.z, xb.w,
                     xc.x, xc.y, xc.z, xc.w };
    #pragma unroll
    for (int m = 0; m < 12; ++m) {
      wh[m][0] += xv[m] * wq.x;
      wh[m][1] += xv[m] * wq.y;
      wh[m][2] += xv[m] * wq.z;
      wh[m][3] += xv[m] * wq.w;
    }
  }
  #pragma unroll
  for (int m = 0; m < 12; ++m) {
    #pragma unroll
    for (int q = 0; q < 4; ++q) {
      float x = wh[m][q];
      x += __shfl_xor(x, 16);
      x += __shfl_xor(x, 32);
      wh[m][q] = x;
    }
  }
  if (l < 16) {
    #pragma unroll
    for (int m = 0; m < 12; ++m) {
      float4 vv = make_float4(wh[m][0], wh[m][1], wh[m][2], wh[m][3]);
      *reinterpret_cast<float4*>(&whp[w * 768 + m * 64 + kc]) = vv;
    }
  }
  __syncthreads();
  #pragma unroll
  for (int c = 0; c < 3; ++c) {
    int o = c * 256 + t;
    whl[o] = whp[o] + whp[768 + o] + whp[1536 + o] + whp[2304 + o];
  }
  // e1 at adjacency rows
  for (int r = w; r < R; r += 4) {
    int row = shdr[H_ROWS + r];
    float p = 0.f;
    #pragma unroll
    for (int s = 0; s < 4; ++s) {
      int f = s * 64 + l;
      p += X[row * 256 + f] * w1l[f];
    }
    #pragma unroll
    for (int d = 1; d < 64; d <<= 1) p += __shfl_xor(p, d);
    if (l == 0) e1r[r] = p;
  }
  // e2 matvec over X^T (L2-resident; 8B/lane coalesced)
  {
    const float2* XT2 = reinterpret_cast<const float2*>(wsf + XT_OFF);
    float a0 = 0.f, a1 = 0.f;
    #pragma unroll 8
    for (int f = 0; f < 256; ++f) {
      float2 xv = XT2[f * 256 + t];
      float wf = w2l[f];
      a0 += xv.x * wf; a1 += xv.y * wf;
    }
    e2s[2 * t] = a0; e2s[2 * t + 1] = a1;
  }
  __syncthreads();

  // softmax stats
  {
    float p = fmaxf(e2s[w * 128 + l], e2s[w * 128 + 64 + l]);
    #pragma unroll
    for (int d = 1; d < 64; d <<= 1) p = fmaxf(p, __shfl_xor(p, d));
    if (l == 0) redv[w] = p;
  }
  __syncthreads();
  float maxe2 = fmaxf(fmaxf(redv[0], redv[1]), fmaxf(redv[2], redv[3]));
  for (int r = 0; r < R; ++r) {
    float e1_ = e1r[r];
    float m_ = leaky_(e1_ + maxe2);
    float pe = __expf(leaky_(e1_ + e2s[t]) - m_) + __expf(leaky_(e1_ + e2s[t + 256]) - m_);
    #pragma unroll
    for (int d = 1; d < 64; d <<= 1) pe += __shfl_xor(pe, d);
    if (l == 0) redf[r * 4 + w] = pe;
    if (t == r) mr12[r] = m_;
  }
  __syncthreads();
  if (t < R) sr12[t] = redf[t * 4] + redf[t * 4 + 1] + redf[t * 4 + 2] + redf[t * 4 + 3];
  __syncthreads();
  if (t < M) {
    int r = shdr[H_ER + t];
    av12[t] = __expf(leaky_(e1r[r] + e2s[shdr[H_EJ + t]]) - mr12[r]) / sr12[r];
  }
  __syncthreads();
  for (int r = w; r < R; r += 4) {
    float a = 0.f;
    #pragma unroll
    for (int m = 0; m < 12; ++m) {
      if (m < M && shdr[H_ER + m] == r) a += av12[m] * whl[m * 64 + l];
    }
    wsf[MIDC_OFF + r * 32768 + b * 64 + l] = elu_(a);
  }
}

// K4: Wh2 partials: block b covers mid columns [b*256, b*256+256)
__global__ void k4_wh2(const float* __restrict__ Wout, float* __restrict__ wsf) {
  __shared__ __align__(16) float midT[256 * 12];
  __shared__ float whp[4][768];
  int b = blockIdx.x, t = threadIdx.x;
  int l = t & 63, w = t >> 6;
  const int* ip = (const int*)(wsf + INT_OFF);
  int R = ip[H_R];
  #pragma unroll
  for (int m = 0; m < 12; ++m) {
    float v = 0.f;
    if (m < R) v = wsf[MIDC_OFF + m * 32768 + b * 256 + t];
    midT[t * 12 + m] = v;
  }
  __syncthreads();
  float acc[12];
  #pragma unroll
  for (int m = 0; m < 12; ++m) acc[m] = 0.f;
  #pragma unroll 2
  for (int ci = 0; ci < 64; ++ci) {
    int cc = w * 64 + ci;
    float wv = Wout[(b * 256 + cc) * 64 + l];
    const float4* xr = reinterpret_cast<const float4*>(&midT[cc * 12]);
    float4 xa = xr[0], xb = xr[1], xc = xr[2];
    acc[0] += xa.x * wv; acc[1] += xa.y * wv; acc[2]  += xa.z * wv; acc[3]  += xa.w * wv;
    acc[4] += xb.x * wv; acc[5] += xb.y * wv; acc[6]  += xb.z * wv; acc[7]  += xb.w * wv;
    acc[8] += xc.x * wv; acc[9] += xc.y * wv; acc[10] += xc.z * wv; acc[11] += xc.w * wv;
  }
  #pragma unroll
  for (int m = 0; m < 12; ++m) whp[w][m * 64 + l] = acc[m];
  __syncthreads();
  #pragma unroll
  for (int c = 0; c < 3; ++c) {
    int o = c * 256 + t;
    float s = whp[0][o] + whp[1][o] + whp[2][o] + whp[3][o];
    wsf[PART_OFF + b * 768 + o] = s;
  }
}

// K5: reduce Wh2 partials; layer-2 closed-form softmax; final elu(V*elu(out2))
__global__ void k5_final(const float* __restrict__ aout, const float* __restrict__ V,
                         float* __restrict__ wsf, float* __restrict__ out) {
  __shared__ float Wh2[768];
  __shared__ float e1o[12], e2o[12], mr[12], sr[12], avals[12];
  int t = threadIdx.x;
  const int* ip = (const int*)(wsf + INT_OFF);
  int M = ip[H_M], R = ip[H_R];
  for (int o = t, c = 0; c < 3; ++c, o += 256) {
    float s = 0.f;
    #pragma unroll 8
    for (int bb = 0; bb < 128; ++bb) s += wsf[PART_OFF + bb * 768 + o];
    Wh2[o] = s;
  }
  __syncthreads();
  if (t < R) {
    float s1 = 0.f, s2 = 0.f;
    for (int k = 0; k < 64; ++k) {
      float wv = Wh2[t * 64 + k];
      s1 += wv * aout[k];
      s2 += wv * aout[64 + k];
    }
    e1o[t] = s1; e2o[t] = s2;
  }
  __syncthreads();
  if (t < R) {
    float maxe = 0.f;  // includes (512-R) implicit zeros
    for (int r = 0; r < R; ++r) maxe = fmaxf(maxe, e2o[r]);
    float m_ = leaky_(e1o[t] + maxe);
    float s = (float)(512 - R) * __expf(leaky_(e1o[t]) - m_);
    for (int r = 0; r < R; ++r) s += __expf(leaky_(e1o[t] + e2o[r]) - m_);
    mr[t] = m_; sr[t] = s;
  }
  __syncthreads();
  if (t < M) {
    int r = ip[H_ER + t];
    int cj = ip[H_ECJ + t];
    float e2v = (cj >= 0) ? e2o[cj] : 0.f;
    avals[t] = __expf(leaky_(e1o[r] + e2v) - mr[r]) / sr[r];
  }
  __syncthreads();
  int l = t & 63, w = t >> 6;
  for (int r = w; r < R; r += 4) {
    float a = 0.f;
    #pragma unroll
    for (int m = 0; m < 12; ++m) {
      if (m < M && ip[H_ER + m] == r) {
        int cj = ip[H_ECJ + m];
        float wv = (cj >= 0) ? Wh2[cj * 64 + l] : 0.f;
        a += avals[m] * wv;
      }
    }
    int row = ip[H_ROWS + r];
    float o2 = elu_(a);
    out[262144 + row * 64 + l] = elu_(V[row * 64 + l] * o2);
  }
}

extern "C" void kernel_launch(void* const* d_in, const int* in_sizes, int n_in,
                              void* d_out, int out_size, void* d_ws, size_t ws_size,
                              hipStream_t stream) {
  const float* X    = (const float*)d_in[0];
  const float* Wst  = (const float*)d_in[1];
  const float* ast  = (const float*)d_in[2];
  const float* Wout = (const float*)d_in[3];
  const float* aout = (const float*)d_in[4];
  const float* V    = (const float*)d_in[5];
  float* out = (float*)d_out;
  float* wsf = (float*)d_ws;

  k1_prep  <<<544, 256, 0, stream>>>(V, X, wsf, out);
  k2_header<<<1,   256, 0, stream>>>(wsf);
  k3_heads <<<512, 256, 0, stream>>>(X, Wst, ast, wsf, out);
  k4_wh2   <<<128, 256, 0, stream>>>(Wout, wsf);
  k5_final <<<1,   256, 0, stream>>>(aout, V, wsf, out);
}

// Round 5
// 142.701 us; speedup vs baseline: 2.7319x; 1.1566x over previous
//
#include <hip/hip_runtime.h>

// ---------------- problem constants ----------------
// N=512 nodes/heads, F_IN=256, H=64, C=64, K=12, ALPHA=0.2
// d_out: adj (512x512) followed by out (512x64), float32

// ---------------- ws float offsets ----------------
#define CAND_OFF 0        // 512*12 float2 = 12288 floats (val, idx-bits)
#define XT_OFF   12288    // 131072 : X^T [256][512]
#define KTH_OFF  143360   // 1 (padded to 64)
#define INT_OFF  143424   // 64 int slots (header)
#define MIDC_OFF 143488   // 12*32768 : compact mid rows
#define PART_OFF 536704   // 128*768  : Wh2 partials [block][o]

// header int indices
#define H_M    0
#define H_R    1
#define H_ROWS 2
#define H_ER   14
#define H_EJ   26
#define H_ECJ  38

__device__ __forceinline__ float leaky_(float x) { return fmaxf(x, 0.2f * x); }
__device__ __forceinline__ float elu_(float x)   { return x > 0.f ? x : __expf(x) - 1.f; }

// K1: blocks 0..511: A row b = V[b]·V^T -> d_out, per-row top-12 candidates,
//     zero out-section (b<128). Blocks 512..543: X^T 64x64 tile transpose.
__global__ __launch_bounds__(256) void k1_prep(const float* __restrict__ V,
                                               const float* __restrict__ X,
                                               float* __restrict__ wsf,
                                               float* __restrict__ out) {
  int b = blockIdx.x, t = threadIdx.x, l = t & 63, w = t >> 6;
  if (b < 512) {
    __shared__ float vi[64];
    __shared__ float redv[4]; __shared__ int redi[4];
    __shared__ float candv[12]; __shared__ int candi[12];
    if (t < 64) vi[t] = V[b * 64 + t];
    __syncthreads();
    float vr0, vr1;
    {
      const float4* vj = reinterpret_cast<const float4*>(V + t * 64);
      float acc = 0.f;
      #pragma unroll
      for (int q = 0; q < 16; ++q) {
        float4 v4 = vj[q];
        acc += v4.x * vi[q*4] + v4.y * vi[q*4+1] + v4.z * vi[q*4+2] + v4.w * vi[q*4+3];
      }
      vr0 = acc;
    }
    {
      const float4* vj = reinterpret_cast<const float4*>(V + (t + 256) * 64);
      float acc = 0.f;
      #pragma unroll
      for (int q = 0; q < 16; ++q) {
        float4 v4 = vj[q];
        acc += v4.x * vi[q*4] + v4.y * vi[q*4+1] + v4.z * vi[q*4+2] + v4.w * vi[q*4+3];
      }
      vr1 = acc;
    }
    out[b * 512 + t]       = vr0;
    out[b * 512 + 256 + t] = vr1;
    if (b < 128) out[262144 + b * 256 + t] = 0.f;

    float v0 = vr0, v1 = vr1;
    int j0 = t, j1 = t + 256;
    for (int round = 0; round < 12; ++round) {
      float m; int mi;
      if (v0 >= v1) { m = v0; mi = j0; } else { m = v1; mi = j1; }
      #pragma unroll
      for (int d = 1; d < 64; d <<= 1) {
        float ov = __shfl_xor(m, d);
        int   oi = __shfl_xor(mi, d);
        if (ov > m || (ov == m && oi < mi)) { m = ov; mi = oi; }
      }
      if (l == 0) { redv[w] = m; redi[w] = mi; }
      __syncthreads();
      float bm = redv[0]; int bi = redi[0];
      #pragma unroll
      for (int ww = 1; ww < 4; ++ww)
        if (redv[ww] > bm || (redv[ww] == bm && redi[ww] < bi)) { bm = redv[ww]; bi = redi[ww]; }
      if (t == 0) { candv[round] = bm; candi[round] = bi; }
      if (bi == j0) v0 = -INFINITY;
      if (bi == j1) v1 = -INFINITY;
      __syncthreads();
    }
    if (t < 12) {
      float2 c; c.x = candv[t]; c.y = __int_as_float(b * 512 + candi[t]);
      *reinterpret_cast<float2*>(wsf + CAND_OFF + (b * 12 + t) * 2) = c;
    }
  } else {
    __shared__ float tile[64][65];
    int ti = b - 512;          // 0..31
    int tjj = ti & 7;          // j-tile
    int tff = ti >> 3;         // f-tile
    int r = t >> 2, c0 = (t & 3) * 16;
    #pragma unroll
    for (int u = 0; u < 4; ++u) {
      float4 x4 = *reinterpret_cast<const float4*>(X + (tjj*64 + r)*256 + tff*64 + c0 + u*4);
      tile[c0+u*4+0][r] = x4.x; tile[c0+u*4+1][r] = x4.y;
      tile[c0+u*4+2][r] = x4.z; tile[c0+u*4+3][r] = x4.w;
    }
    __syncthreads();
    int fl = t >> 2, jc0 = (t & 3) * 16;
    #pragma unroll
    for (int u = 0; u < 4; ++u) {
      float4 o4 = make_float4(tile[fl][jc0+u*4+0], tile[fl][jc0+u*4+1],
                              tile[fl][jc0+u*4+2], tile[fl][jc0+u*4+3]);
      *reinterpret_cast<float4*>(wsf + XT_OFF + (tff*64 + fl)*512 + tjj*64 + jc0 + u*4) = o4;
    }
  }
}

// K2: single block: 6144 candidates -> global top-12 -> kth + header.
// Register-resident (static indices + removal bitmask), coalesced loads,
// parallel ballot-based header build. No runtime-indexed thread-local arrays.
__global__ void k2_header(float* __restrict__ wsf) {
  __shared__ float redv[4]; __shared__ int redi[4];
  __shared__ float candv[12]; __shared__ int candi[12];
  __shared__ int es_s[12], rows_s[12];
  __shared__ int M_s, R_s;
  int t = threadIdx.x, l = t & 63, w = t >> 6;

  float v[24]; int ix[24];
  const float2* cp = reinterpret_cast<const float2*>(wsf + CAND_OFF);
  #pragma unroll
  for (int k = 0; k < 24; ++k) {
    float2 c = cp[k * 256 + t];          // coalesced: lane-consecutive float2
    v[k] = c.x; ix[k] = __float_as_int(c.y);
  }
  unsigned rm = 0;
  for (int round = 0; round < 12; ++round) {
    float m = -INFINITY; int mi = 0x7FFFFFFF; int sel = -1;
    #pragma unroll
    for (int k = 0; k < 24; ++k) {
      bool ok = ((rm >> k) & 1u) == 0u;
      bool better = ok && (v[k] > m || (v[k] == m && ix[k] < mi));
      if (better) { m = v[k]; mi = ix[k]; sel = k; }
    }
    float lm = m; int lmi = mi; (void)lm;
    #pragma unroll
    for (int d = 1; d < 64; d <<= 1) {
      float ov = __shfl_xor(m, d);
      int   oi = __shfl_xor(mi, d);
      if (ov > m || (ov == m && oi < mi)) { m = ov; mi = oi; }
    }
    if (l == 0) { redv[w] = m; redi[w] = mi; }
    __syncthreads();
    float bm = redv[0]; int bi = redi[0];
    #pragma unroll
    for (int ww = 1; ww < 4; ++ww)
      if (redv[ww] > bm || (redv[ww] == bm && redi[ww] < bi)) { bm = redv[ww]; bi = redi[ww]; }
    if (t == 0) { candv[round] = bm; candi[round] = bi; }
    if (sel >= 0 && lmi == bi) rm |= 1u << sel;   // unique global index -> one owner
    __syncthreads();
  }

  // ---- parallel header build (wave 0 lanes 0..11 do the work) ----
  float kv = candv[11];
  bool valid = (t < 12) && (candv[t] > kv);
  int myidx = valid ? candi[t] : 0x7FFFFFFF;
  unsigned long long vm = __ballot(valid);       // wave 0's value is the real one
  if (t < 12) {
    int rank = 0;
    #pragma unroll
    for (int q = 0; q < 12; ++q)
      if (((vm >> q) & 1ull) && candi[q] < myidx) ++rank;
    if (valid) es_s[rank] = myidx;
    if (t == 0) M_s = (int)__popcll(vm & 0xFFFull);
  }
  __syncthreads();
  int M = M_s;
  bool isent = (t < M);
  int i2 = isent ? (es_s[t] >> 9) : -1;
  int j2 = isent ? (es_s[t] & 511) : 0;
  bool isnew = isent && (t == 0 || (es_s[t - 1] >> 9) != i2);
  unsigned long long nm = __ballot(isnew);
  if (isnew) {
    int r = (int)__popcll(nm & ((1ull << t) - 1ull));
    rows_s[r] = i2;
  }
  if (t == 0) R_s = (int)__popcll(nm & 0xFFFull);
  __syncthreads();
  int R = R_s;
  int* ip = (int*)(wsf + INT_OFF);
  if (t == 0) { ip[H_M] = M; ip[H_R] = R; wsf[KTH_OFF] = kv; }
  if (t < 12) {
    ip[H_ROWS + t] = (t < R) ? rows_s[t] : 0;
    int er = 0, ecj = -1;
    if (isent) {
      er = (int)__popcll(nm & ((2ull << t) - 1ull)) - 1;
      for (int r = 0; r < R; ++r) if (rows_s[r] == j2) ecj = r;
    }
    ip[H_ER + t]  = er;
    ip[H_EJ + t]  = isent ? j2 : 0;
    ip[H_ECJ + t] = ecj;
  }
}

// K3: one block per head h=b. adj row write; W read ONCE -> w1/w2, Wh@entries,
// e1; e2 matvec over L2-resident X^T; softmax stats; mid_c write.
__global__ __launch_bounds__(256) void k3_heads(
    const float* __restrict__ X, const float* __restrict__ Wst,
    const float* __restrict__ ast, float* __restrict__ wsf,
    float* __restrict__ out) {
  __shared__ int   shdr[64];
  __shared__ __align__(16) float XeT[3072];   // [f][m]
  __shared__ __align__(16) float whp[3072];
  __shared__ float w1l[256], w2l[256];
  __shared__ float e2s[512];
  __shared__ float whl[768];
  __shared__ float e1r[12], mr12[12], sr12[12], av12[12];
  __shared__ float redv[4], redf[48];

  int b = blockIdx.x, t = threadIdx.x, l = t & 63, w = t >> 6;
  const int* ip = (const int*)(wsf + INT_OFF);

  // adj row write (independent of header)
  {
    float kv = wsf[KTH_OFF];
    float a0 = out[b * 512 + t], a1 = out[b * 512 + 256 + t];
    out[b * 512 + t]       = (a0 > kv) ? 1.f : 0.f;
    out[b * 512 + 256 + t] = (a1 > kv) ? 1.f : 0.f;
  }
  if (t < 50) shdr[t] = ip[t];
  __syncthreads();
  int M = shdr[H_M], R = shdr[H_R];

  #pragma unroll
  for (int m = 0; m < 12; ++m) {
    float v = 0.f;
    if (m < M) v = X[shdr[H_EJ + m] * 256 + t];
    XeT[t * 12 + m] = v;
  }
  __syncthreads();

  // W pass: W_h read once; w1/w2 (k-reduce) + Wh@entries (f-reduce partials)
  const float* Wb = Wst + b * 16384;
  int fg = l >> 4, kc = (l & 15) << 2;
  float4 a1q = *reinterpret_cast<const float4*>(ast + b * 128 + kc);
  float4 a2q = *reinterpret_cast<const float4*>(ast + b * 128 + 64 + kc);
  float wh[12][4];
  #pragma unroll
  for (int m = 0; m < 12; ++m) { wh[m][0] = wh[m][1] = wh[m][2] = wh[m][3] = 0.f; }

  #pragma unroll 4
  for (int it = 0; it < 16; ++it) {
    int f = w * 64 + it * 4 + fg;
    float4 wq = *reinterpret_cast<const float4*>(Wb + f * 64 + kc);
    float p1 = wq.x*a1q.x + wq.y*a1q.y + wq.z*a1q.z + wq.w*a1q.w;
    float p2 = wq.x*a2q.x + wq.y*a2q.y + wq.z*a2q.z + wq.w*a2q.w;
    #pragma unroll
    for (int d = 1; d < 16; d <<= 1) { p1 += __shfl_xor(p1, d); p2 += __shfl_xor(p2, d); }
    if ((l & 15) == 0) { w1l[f] = p1; w2l[f] = p2; }
    const float4* xr = reinterpret_cast<const float4*>(&XeT[f * 12]);
    float4 xa = xr[0], xb = xr[1], xc = xr[2];
    float xv[12] = { xa.x, xa.y, xa.z, xa.w, xb.x, xb.y, xb.z, xb.w,
                     xc.x, xc.y, xc.z, xc.w };
    #pragma unroll
    for (int m = 0; m < 12; ++m) {
      wh[m][0] += xv[m] * wq.x;
      wh[m][1] += xv[m] * wq.y;
      wh[m][2] += xv[m] * wq.z;
      wh[m][3] += xv[m] * wq.w;
    }
  }
  #pragma unroll
  for (int m = 0; m < 12; ++m) {
    #pragma unroll
    for (int q = 0; q < 4; ++q) {
      float x = wh[m][q];
      x += __shfl_xor(x, 16);
      x += __shfl_xor(x, 32);
      wh[m][q] = x;
    }
  }
  if (l < 16) {
    #pragma unroll
    for (int m = 0; m < 12; ++m) {
      float4 vv = make_float4(wh[m][0], wh[m][1], wh[m][2], wh[m][3]);
      *reinterpret_cast<float4*>(&whp[w * 768 + m * 64 + kc]) = vv;
    }
  }
  __syncthreads();
  #pragma unroll
  for (int c = 0; c < 3; ++c) {
    int o = c * 256 + t;
    whl[o] = whp[o] + whp[768 + o] + whp[1536 + o] + whp[2304 + o];
  }
  // e1 at adjacency rows
  for (int r = w; r < R; r += 4) {
    int row = shdr[H_ROWS + r];
    float p = 0.f;
    #pragma unroll
    for (int s = 0; s < 4; ++s) {
      int f = s * 64 + l;
      p += X[row * 256 + f] * w1l[f];
    }
    #pragma unroll
    for (int d = 1; d < 64; d <<= 1) p += __shfl_xor(p, d);
    if (l == 0) e1r[r] = p;
  }
  // e2 matvec over X^T (L2-resident; 8B/lane coalesced)
  {
    const float2* XT2 = reinterpret_cast<const float2*>(wsf + XT_OFF);
    float a0 = 0.f, a1 = 0.f;
    #pragma unroll 8
    for (int f = 0; f < 256; ++f) {
      float2 xv = XT2[f * 256 + t];
      float wf = w2l[f];
      a0 += xv.x * wf; a1 += xv.y * wf;
    }
    e2s[2 * t] = a0; e2s[2 * t + 1] = a1;
  }
  __syncthreads();

  // softmax stats
  {
    float p = fmaxf(e2s[w * 128 + l], e2s[w * 128 + 64 + l]);
    #pragma unroll
    for (int d = 1; d < 64; d <<= 1) p = fmaxf(p, __shfl_xor(p, d));
    if (l == 0) redv[w] = p;
  }
  __syncthreads();
  float maxe2 = fmaxf(fmaxf(redv[0], redv[1]), fmaxf(redv[2], redv[3]));
  for (int r = 0; r < R; ++r) {
    float e1_ = e1r[r];
    float m_ = leaky_(e1_ + maxe2);
    float pe = __expf(leaky_(e1_ + e2s[t]) - m_) + __expf(leaky_(e1_ + e2s[t + 256]) - m_);
    #pragma unroll
    for (int d = 1; d < 64; d <<= 1) pe += __shfl_xor(pe, d);
    if (l == 0) redf[r * 4 + w] = pe;
    if (t == r) mr12[r] = m_;
  }
  __syncthreads();
  if (t < R) sr12[t] = redf[t * 4] + redf[t * 4 + 1] + redf[t * 4 + 2] + redf[t * 4 + 3];
  __syncthreads();
  if (t < M) {
    int r = shdr[H_ER + t];
    av12[t] = __expf(leaky_(e1r[r] + e2s[shdr[H_EJ + t]]) - mr12[r]) / sr12[r];
  }
  __syncthreads();
  for (int r = w; r < R; r += 4) {
    float a = 0.f;
    #pragma unroll
    for (int m = 0; m < 12; ++m) {
      if (m < M && shdr[H_ER + m] == r) a += av12[m] * whl[m * 64 + l];
    }
    wsf[MIDC_OFF + r * 32768 + b * 64 + l] = elu_(a);
  }
}

// K4: Wh2 partials: block b covers mid columns [b*256, b*256+256)
__global__ void k4_wh2(const float* __restrict__ Wout, float* __restrict__ wsf) {
  __shared__ __align__(16) float midT[256 * 12];
  __shared__ float whp[4][768];
  int b = blockIdx.x, t = threadIdx.x;
  int l = t & 63, w = t >> 6;
  const int* ip = (const int*)(wsf + INT_OFF);
  int R = ip[H_R];
  #pragma unroll
  for (int m = 0; m < 12; ++m) {
    float v = 0.f;
    if (m < R) v = wsf[MIDC_OFF + m * 32768 + b * 256 + t];
    midT[t * 12 + m] = v;
  }
  __syncthreads();
  float acc[12];
  #pragma unroll
  for (int m = 0; m < 12; ++m) acc[m] = 0.f;
  #pragma unroll 2
  for (int ci = 0; ci < 64; ++ci) {
    int cc = w * 64 + ci;
    float wv = Wout[(b * 256 + cc) * 64 + l];
    const float4* xr = reinterpret_cast<const float4*>(&midT[cc * 12]);
    float4 xa = xr[0], xb = xr[1], xc = xr[2];
    acc[0] += xa.x * wv; acc[1] += xa.y * wv; acc[2]  += xa.z * wv; acc[3]  += xa.w * wv;
    acc[4] += xb.x * wv; acc[5] += xb.y * wv; acc[6]  += xb.z * wv; acc[7]  += xb.w * wv;
    acc[8] += xc.x * wv; acc[9] += xc.y * wv; acc[10] += xc.z * wv; acc[11] += xc.w * wv;
  }
  #pragma unroll
  for (int m = 0; m < 12; ++m) whp[w][m * 64 + l] = acc[m];
  __syncthreads();
  #pragma unroll
  for (int c = 0; c < 3; ++c) {
    int o = c * 256 + t;
    float s = whp[0][o] + whp[1][o] + whp[2][o] + whp[3][o];
    wsf[PART_OFF + b * 768 + o] = s;
  }
}

// K5: reduce Wh2 partials; layer-2 closed-form softmax; final elu(V*elu(out2))
__global__ void k5_final(const float* __restrict__ aout, const float* __restrict__ V,
                         float* __restrict__ wsf, float* __restrict__ out) {
  __shared__ float Wh2[768];
  __shared__ float e1o[12], e2o[12], mr[12], sr[12], avals[12];
  int t = threadIdx.x;
  const int* ip = (const int*)(wsf + INT_OFF);
  int M = ip[H_M], R = ip[H_R];
  for (int o = t, c = 0; c < 3; ++c, o += 256) {
    float s = 0.f;
    #pragma unroll 8
    for (int bb = 0; bb < 128; ++bb) s += wsf[PART_OFF + bb * 768 + o];
    Wh2[o] = s;
  }
  __syncthreads();
  if (t < R) {
    float s1 = 0.f, s2 = 0.f;
    for (int k = 0; k < 64; ++k) {
      float wv = Wh2[t * 64 + k];
      s1 += wv * aout[k];
      s2 += wv * aout[64 + k];
    }
    e1o[t] = s1; e2o[t] = s2;
  }
  __syncthreads();
  if (t < R) {
    float maxe = 0.f;  // includes (512-R) implicit zeros
    for (int r = 0; r < R; ++r) maxe = fmaxf(maxe, e2o[r]);
    float m_ = leaky_(e1o[t] + maxe);
    float s = (float)(512 - R) * __expf(leaky_(e1o[t]) - m_);
    for (int r = 0; r < R; ++r) s += __expf(leaky_(e1o[t] + e2o[r]) - m_);
    mr[t] = m_; sr[t] = s;
  }
  __syncthreads();
  if (t < M) {
    int r = ip[H_ER + t];
    int cj = ip[H_ECJ + t];
    float e2v = (cj >= 0) ? e2o[cj] : 0.f;
    avals[t] = __expf(leaky_(e1o[r] + e2v) - mr[r]) / sr[r];
  }
  __syncthreads();
  int l = t & 63, w = t >> 6;
  for (int r = w; r < R; r += 4) {
    float a = 0.f;
    #pragma unroll
    for (int m = 0; m < 12; ++m) {
      if (m < M && ip[H_ER + m] == r) {
        int cj = ip[H_ECJ + m];
        float wv = (cj >= 0) ? Wh2[cj * 64 + l] : 0.f;
        a += avals[m] * wv;
      }
    }
    int row = ip[H_ROWS + r];
    float o2 = elu_(a);
    out[262144 + row * 64 + l] = elu_(V[row * 64 + l] * o2);
  }
}

extern "C" void kernel_launch(void* const* d_in, const int* in_sizes, int n_in,
                              void* d_out, int out_size, void* d_ws, size_t ws_size,
                              hipStream_t stream) {
  const float* X    = (const float*)d_in[0];
  const float* Wst  = (const float*)d_in[1];
  const float* ast  = (const float*)d_in[2];
  const float* Wout = (const float*)d_in[3];
  const float* aout = (const float*)d_in[4];
  const float* V    = (const float*)d_in[5];
  float* out = (float*)d_out;
  float* wsf = (float*)d_ws;

  k1_prep  <<<544, 256, 0, stream>>>(V, X, wsf, out);
  k2_header<<<1,   256, 0, stream>>>(wsf);
  k3_heads <<<512, 256, 0, stream>>>(X, Wst, ast, wsf, out);
  k4_wh2   <<<128, 256, 0, stream>>>(Wout, wsf);
  k5_final <<<1,   256, 0, stream>>>(aout, V, wsf, out);
}

// Round 6
// 140.668 us; speedup vs baseline: 2.7714x; 1.0145x over previous
//
#include <hip/hip_runtime.h>

// ---------------- problem constants ----------------
// N=512 nodes/heads, F_IN=256, H=64, C=64, K=12, ALPHA=0.2
// d_out: adj (512x512) followed by out (512x64), float32

// ---------------- ws float offsets ----------------
#define CAND_OFF 0        // 512*12 float2 = 12288 floats
#define XT_OFF   12288    // 131072 : X^T [256][512]
#define KTH_OFF  143360   // 1 (padded to 64)
#define INT_OFF  143424   // 64 int slots (header + ticket)
#define W1_OFF   143488   // 512*256 : w1[h][f]
#define W2_OFF   274560   // 512*256 : w2[h][f]
#define E2P_OFF  405632   // 4*512*512 : E2 f-quarter partials [q][h][j]
#define MIDC_OFF 1454208  // 12*32768 : compact mid rows
#define PART_OFF 1847424  // 128*768  : Wh2 partials [block][o]

// header int indices
#define H_M      0
#define H_R      1
#define H_ROWS   2
#define H_ER     14
#define H_EJ     26
#define H_ECJ    38
#define H_TICKET 60

__device__ __forceinline__ float leaky_(float x) { return fmaxf(x, 0.2f * x); }
__device__ __forceinline__ float elu_(float x)   { return x > 0.f ? x : __expf(x) - 1.f; }

// K1: blocks 0..511: A row b = V[b]·V^T + per-row top-12 (wave-local, 1 barrier)
//     blocks 512..543: X^T tile transpose
//     blocks 544..1055: w1/w2 for head (b-544) — W_stack streamed, deferred reduce
__global__ __launch_bounds__(256) void k1_prep(const float* __restrict__ V,
                                               const float* __restrict__ X,
                                               const float* __restrict__ Wst,
                                               const float* __restrict__ ast,
                                               float* __restrict__ wsf,
                                               float* __restrict__ out) {
  __shared__ float vi[64];
  __shared__ float wv[48]; __shared__ int wi[48];
  __shared__ float tile[64][65];
  int b = blockIdx.x, t = threadIdx.x, l = t & 63, w = t >> 6;

  if (b < 512) {
    if (b == 0 && t == 0) ((int*)(wsf + INT_OFF))[H_TICKET] = 0;  // reset k4 ticket each call
    if (t < 64) vi[t] = V[b * 64 + t];
    __syncthreads();
    float vr0, vr1;
    {
      const float4* vj = reinterpret_cast<const float4*>(V + t * 64);
      float acc = 0.f;
      #pragma unroll
      for (int q = 0; q < 16; ++q) {
        float4 v4 = vj[q];
        acc += v4.x * vi[q*4] + v4.y * vi[q*4+1] + v4.z * vi[q*4+2] + v4.w * vi[q*4+3];
      }
      vr0 = acc;
    }
    {
      const float4* vj = reinterpret_cast<const float4*>(V + (t + 256) * 64);
      float acc = 0.f;
      #pragma unroll
      for (int q = 0; q < 16; ++q) {
        float4 v4 = vj[q];
        acc += v4.x * vi[q*4] + v4.y * vi[q*4+1] + v4.z * vi[q*4+2] + v4.w * vi[q*4+3];
      }
      vr1 = acc;
    }
    out[b * 512 + t]       = vr0;
    out[b * 512 + 256 + t] = vr1;
    if (b < 128) out[262144 + b * 256 + t] = 0.f;

    // wave-local top-12 (no barriers inside rounds)
    float v0 = vr0, v1 = vr1;
    int j0 = t, j1 = t + 256;
    for (int round = 0; round < 12; ++round) {
      float m; int mi;
      if (v0 >= v1) { m = v0; mi = j0; } else { m = v1; mi = j1; }
      #pragma unroll
      for (int d = 1; d < 64; d <<= 1) {
        float ov = __shfl_xor(m, d);
        int   oi = __shfl_xor(mi, d);
        if (ov > m || (ov == m && oi < mi)) { m = ov; mi = oi; }
      }
      if (l == 0) { wv[w * 12 + round] = m; wi[w * 12 + round] = mi; }
      if (mi == j0) v0 = -INFINITY;
      if (mi == j1) v1 = -INFINITY;
    }
    __syncthreads();
    if (w == 0) {
      float cv = (l < 48) ? wv[l] : -INFINITY;
      int   ci = (l < 48) ? wi[l] : 0x7FFFFFFF;
      for (int round = 0; round < 12; ++round) {
        float m = cv; int mi = ci;
        #pragma unroll
        for (int d = 1; d < 64; d <<= 1) {
          float ov = __shfl_xor(m, d);
          int   oi = __shfl_xor(mi, d);
          if (ov > m || (ov == m && oi < mi)) { m = ov; mi = oi; }
        }
        if (l == 0) {
          float2 c; c.x = m; c.y = __int_as_float(b * 512 + mi);
          *reinterpret_cast<float2*>(wsf + CAND_OFF + (b * 12 + round) * 2) = c;
        }
        if (ci == mi) cv = -INFINITY;   // indices unique within block
      }
    }
  } else if (b < 544) {
    int ti = b - 512;
    int tjj = ti & 7, tff = ti >> 3;
    int r = t >> 2, c0 = (t & 3) * 16;
    #pragma unroll
    for (int u = 0; u < 4; ++u) {
      float4 x4 = *reinterpret_cast<const float4*>(X + (tjj*64 + r)*256 + tff*64 + c0 + u*4);
      tile[c0+u*4+0][r] = x4.x; tile[c0+u*4+1][r] = x4.y;
      tile[c0+u*4+2][r] = x4.z; tile[c0+u*4+3][r] = x4.w;
    }
    __syncthreads();
    int fl = t >> 2, jc0 = (t & 3) * 16;
    #pragma unroll
    for (int u = 0; u < 4; ++u) {
      float4 o4 = make_float4(tile[fl][jc0+u*4+0], tile[fl][jc0+u*4+1],
                              tile[fl][jc0+u*4+2], tile[fl][jc0+u*4+3]);
      *reinterpret_cast<float4*>(wsf + XT_OFF + (tff*64 + fl)*512 + tjj*64 + jc0 + u*4) = o4;
    }
  } else {
    // w1/w2 pass: head h, pure stream of W_h with deferred 16-lane reduction
    int h = b - 544;
    int kc = (t & 15) << 2;
    float4 a1q = *reinterpret_cast<const float4*>(ast + h * 128 + kc);
    float4 a2q = *reinterpret_cast<const float4*>(ast + h * 128 + 64 + kc);
    const float* Wb = Wst + h * 16384;
    float p1a[16], p2a[16];
    #pragma unroll
    for (int it = 0; it < 16; ++it) {
      float4 wq = *reinterpret_cast<const float4*>(Wb + it * 1024 + t * 4);
      p1a[it] = wq.x*a1q.x + wq.y*a1q.y + wq.z*a1q.z + wq.w*a1q.w;
      p2a[it] = wq.x*a2q.x + wq.y*a2q.y + wq.z*a2q.z + wq.w*a2q.w;
    }
    #pragma unroll
    for (int it = 0; it < 16; ++it) {
      float p1 = p1a[it], p2 = p2a[it];
      #pragma unroll
      for (int d = 1; d < 16; d <<= 1) { p1 += __shfl_xor(p1, d); p2 += __shfl_xor(p2, d); }
      if ((t & 15) == 0) {
        int f = it * 16 + (t >> 4);
        wsf[W1_OFF + h * 256 + f] = p1;
        wsf[W2_OFF + h * 256 + f] = p2;
      }
    }
  }
}

// K2: blocks 0..255: E2 f-quarter-partial GEMM (W2 · X^T), round-2 proven code.
//     block 256: header build from 6144 candidates (register-resident, ballot).
__global__ __launch_bounds__(256) void k2_e2hdr(const float* __restrict__ X,
                                                float* __restrict__ wsf) {
  __shared__ __align__(16) float As[64][68];
  __shared__ __align__(16) float Bs[64][68];
  __shared__ float redv[4]; __shared__ int redi[4];
  __shared__ float candv[12]; __shared__ int candi[12];
  __shared__ int es_s[12], rows_s[12];
  __shared__ int M_s, R_s;
  int b = blockIdx.x, t = threadIdx.x, l = t & 63, w = t >> 6;

  if (b < 256) {
    int q = b >> 6, bh = (b >> 3) & 7, bj = b & 7;
    int r = t >> 2, c0 = (t & 3) * 16;
    const float* wsrc = wsf + W2_OFF + (bh * 64 + r) * 256 + q * 64 + c0;
    const float* xsrc = X + (bj * 64 + r) * 256 + q * 64 + c0;
    #pragma unroll
    for (int u = 0; u < 4; ++u) {
      float4 a4 = *reinterpret_cast<const float4*>(wsrc + u * 4);
      float4 b4 = *reinterpret_cast<const float4*>(xsrc + u * 4);
      As[c0 + u*4 + 0][r] = a4.x; As[c0 + u*4 + 1][r] = a4.y;
      As[c0 + u*4 + 2][r] = a4.z; As[c0 + u*4 + 3][r] = a4.w;
      Bs[c0 + u*4 + 0][r] = b4.x; Bs[c0 + u*4 + 1][r] = b4.y;
      Bs[c0 + u*4 + 2][r] = b4.z; Bs[c0 + u*4 + 3][r] = b4.w;
    }
    __syncthreads();
    int th = t >> 4, tj = t & 15;
    float acc[4][4] = {};
    #pragma unroll 8
    for (int f = 0; f < 64; ++f) {
      float4 a4 = *reinterpret_cast<const float4*>(&As[f][th * 4]);
      float4 b4 = *reinterpret_cast<const float4*>(&Bs[f][tj * 4]);
      float av[4] = { a4.x, a4.y, a4.z, a4.w };
      float bv[4] = { b4.x, b4.y, b4.z, b4.w };
      #pragma unroll
      for (int i = 0; i < 4; ++i)
        #pragma unroll
        for (int j = 0; j < 4; ++j)
          acc[i][j] += av[i] * bv[j];
    }
    float* dst = wsf + E2P_OFF + q * 262144 + (bh * 64 + th * 4) * 512 + bj * 64 + tj * 4;
    #pragma unroll
    for (int i = 0; i < 4; ++i) {
      float4 o4 = make_float4(acc[i][0], acc[i][1], acc[i][2], acc[i][3]);
      *reinterpret_cast<float4*>(dst + i * 512) = o4;
    }
    return;
  }

  // ---- header block ----
  float v[24]; int ix[24];
  const float2* cp = reinterpret_cast<const float2*>(wsf + CAND_OFF);
  #pragma unroll
  for (int k = 0; k < 24; ++k) {
    float2 c = cp[k * 256 + t];
    v[k] = c.x; ix[k] = __float_as_int(c.y);
  }
  unsigned rm = 0;
  for (int round = 0; round < 12; ++round) {
    float m = -INFINITY; int mi = 0x7FFFFFFF; int sel = -1;
    #pragma unroll
    for (int k = 0; k < 24; ++k) {
      bool ok = ((rm >> k) & 1u) == 0u;
      bool better = ok && (v[k] > m || (v[k] == m && ix[k] < mi));
      if (better) { m = v[k]; mi = ix[k]; sel = k; }
    }
    int lmi = mi;
    #pragma unroll
    for (int d = 1; d < 64; d <<= 1) {
      float ov = __shfl_xor(m, d);
      int   oi = __shfl_xor(mi, d);
      if (ov > m || (ov == m && oi < mi)) { m = ov; mi = oi; }
    }
    if (l == 0) { redv[w] = m; redi[w] = mi; }
    __syncthreads();
    float bm = redv[0]; int bi = redi[0];
    #pragma unroll
    for (int ww = 1; ww < 4; ++ww)
      if (redv[ww] > bm || (redv[ww] == bm && redi[ww] < bi)) { bm = redv[ww]; bi = redi[ww]; }
    if (t == 0) { candv[round] = bm; candi[round] = bi; }
    if (sel >= 0 && lmi == bi) rm |= 1u << sel;
    __syncthreads();
  }
  float kv = candv[11];
  bool valid = (t < 12) && (candv[t] > kv);
  int myidx = valid ? candi[t] : 0x7FFFFFFF;
  unsigned long long vm = __ballot(valid);
  if (t < 12) {
    int rank = 0;
    #pragma unroll
    for (int q = 0; q < 12; ++q)
      if (((vm >> q) & 1ull) && candi[q] < myidx) ++rank;
    if (valid) es_s[rank] = myidx;
    if (t == 0) M_s = (int)__popcll(vm & 0xFFFull);
  }
  __syncthreads();
  int M = M_s;
  bool isent = (t < M);
  int i2 = isent ? (es_s[t] >> 9) : -1;
  int j2 = isent ? (es_s[t] & 511) : 0;
  bool isnew = isent && (t == 0 || (es_s[t - 1] >> 9) != i2);
  unsigned long long nm = __ballot(isnew);
  if (isnew) {
    int r = (int)__popcll(nm & ((1ull << t) - 1ull));
    rows_s[r] = i2;
  }
  if (t == 0) R_s = (int)__popcll(nm & 0xFFFull);
  __syncthreads();
  int R = R_s;
  int* ip = (int*)(wsf + INT_OFF);
  if (t == 0) { ip[H_M] = M; ip[H_R] = R; wsf[KTH_OFF] = kv; }
  if (t < 12) {
    ip[H_ROWS + t] = (t < R) ? rows_s[t] : 0;
    int er = 0, ecj = -1;
    if (isent) {
      er = (int)__popcll(nm & ((2ull << t) - 1ull)) - 1;
      for (int r = 0; r < R; ++r) if (rows_s[r] == j2) ecj = r;
    }
    ip[H_ER + t]  = er;
    ip[H_EJ + t]  = isent ? j2 : 0;
    ip[H_ECJ + t] = ecj;
  }
}

// K3: one block per head. adj row write; dense W pass (Wh@entries only, no
// cross-lane ops in hot loop); e1 via precomputed w1; E2 row merge; stats; mid.
__global__ __launch_bounds__(256) void k3_heads(
    const float* __restrict__ X, const float* __restrict__ Wst,
    float* __restrict__ wsf, float* __restrict__ out) {
  __shared__ int   shdr[64];
  __shared__ __align__(16) float XeT[3072];
  __shared__ __align__(16) float whp[3072];
  __shared__ float w1l[256];
  __shared__ float e2s[512];
  __shared__ float whl[768];
  __shared__ float e1r[12], mr12[12], sr12[12], av12[12];
  __shared__ float redv[4], redf[48];

  int b = blockIdx.x, t = threadIdx.x, l = t & 63, w = t >> 6;
  const int* ip = (const int*)(wsf + INT_OFF);

  // adj row write
  {
    float kv = wsf[KTH_OFF];
    float a0 = out[b * 512 + t], a1 = out[b * 512 + 256 + t];
    out[b * 512 + t]       = (a0 > kv) ? 1.f : 0.f;
    out[b * 512 + 256 + t] = (a1 > kv) ? 1.f : 0.f;
  }
  if (t < 50) shdr[t] = ip[t];
  w1l[t] = wsf[W1_OFF + b * 256 + t];
  {
    float s0 = 0.f, s1 = 0.f;
    #pragma unroll
    for (int q = 0; q < 4; ++q) {
      s0 += wsf[E2P_OFF + q * 262144 + b * 512 + t];
      s1 += wsf[E2P_OFF + q * 262144 + b * 512 + 256 + t];
    }
    e2s[t] = s0; e2s[t + 256] = s1;
  }
  __syncthreads();
  int M = shdr[H_M], R = shdr[H_R];

  #pragma unroll
  for (int m = 0; m < 12; ++m) {
    float v = 0.f;
    if (m < M) v = X[shdr[H_EJ + m] * 256 + t];
    XeT[t * 12 + m] = v;
  }
  __syncthreads();

  // W pass: pure load+FMA (48 FMA per float4), accumulate Wh@entries
  const float* Wb = Wst + b * 16384;
  int fg = l >> 4, kc = (l & 15) << 2;
  float wh[12][4];
  #pragma unroll
  for (int m = 0; m < 12; ++m) { wh[m][0] = wh[m][1] = wh[m][2] = wh[m][3] = 0.f; }
  #pragma unroll 4
  for (int it = 0; it < 16; ++it) {
    int f = w * 64 + it * 4 + fg;
    float4 wq = *reinterpret_cast<const float4*>(Wb + f * 64 + kc);
    const float4* xr = reinterpret_cast<const float4*>(&XeT[f * 12]);
    float4 xa = xr[0], xb = xr[1], xc = xr[2];
    float xv[12] = { xa.x, xa.y, xa.z, xa.w, xb.x, xb.y, xb.z, xb.w,
                     xc.x, xc.y, xc.z, xc.w };
    #pragma unroll
    for (int m = 0; m < 12; ++m) {
      wh[m][0] += xv[m] * wq.x;
      wh[m][1] += xv[m] * wq.y;
      wh[m][2] += xv[m] * wq.z;
      wh[m][3] += xv[m] * wq.w;
    }
  }
  #pragma unroll
  for (int m = 0; m < 12; ++m) {
    #pragma unroll
    for (int q = 0; q < 4; ++q) {
      float x = wh[m][q];
      x += __shfl_xor(x, 16);
      x += __shfl_xor(x, 32);
      wh[m][q] = x;
    }
  }
  if (l < 16) {
    #pragma unroll
    for (int m = 0; m < 12; ++m) {
      float4 vv = make_float4(wh[m][0], wh[m][1], wh[m][2], wh[m][3]);
      *reinterpret_cast<float4*>(&whp[w * 768 + m * 64 + kc]) = vv;
    }
  }
  __syncthreads();
  #pragma unroll
  for (int c = 0; c < 3; ++c) {
    int o = c * 256 + t;
    whl[o] = whp[o] + whp[768 + o] + whp[1536 + o] + whp[2304 + o];
  }
  // e1 at adjacency rows (w1 precomputed in k1)
  for (int r = w; r < R; r += 4) {
    int row = shdr[H_ROWS + r];
    float p = 0.f;
    #pragma unroll
    for (int s = 0; s < 4; ++s) {
      int f = s * 64 + l;
      p += X[row * 256 + f] * w1l[f];
    }
    #pragma unroll
    for (int d = 1; d < 64; d <<= 1) p += __shfl_xor(p, d);
    if (l == 0) e1r[r] = p;
  }
  __syncthreads();

  // softmax stats
  {
    float p = fmaxf(e2s[w * 128 + l], e2s[w * 128 + 64 + l]);
    #pragma unroll
    for (int d = 1; d < 64; d <<= 1) p = fmaxf(p, __shfl_xor(p, d));
    if (l == 0) redv[w] = p;
  }
  __syncthreads();
  float maxe2 = fmaxf(fmaxf(redv[0], redv[1]), fmaxf(redv[2], redv[3]));
  for (int r = 0; r < R; ++r) {
    float e1_ = e1r[r];
    float m_ = leaky_(e1_ + maxe2);
    float pe = __expf(leaky_(e1_ + e2s[t]) - m_) + __expf(leaky_(e1_ + e2s[t + 256]) - m_);
    #pragma unroll
    for (int d = 1; d < 64; d <<= 1) pe += __shfl_xor(pe, d);
    if (l == 0) redf[r * 4 + w] = pe;
    if (t == r) mr12[r] = m_;
  }
  __syncthreads();
  if (t < R) sr12[t] = redf[t * 4] + redf[t * 4 + 1] + redf[t * 4 + 2] + redf[t * 4 + 3];
  __syncthreads();
  if (t < M) {
    int r = shdr[H_ER + t];
    av12[t] = __expf(leaky_(e1r[r] + e2s[shdr[H_EJ + t]]) - mr12[r]) / sr12[r];
  }
  __syncthreads();
  for (int r = w; r < R; r += 4) {
    float a = 0.f;
    #pragma unroll
    for (int m = 0; m < 12; ++m) {
      if (m < M && shdr[H_ER + m] == r) a += av12[m] * whl[m * 64 + l];
    }
    wsf[MIDC_OFF + r * 32768 + b * 64 + l] = elu_(a);
  }
}

// K4: Wh2 partials (128 blocks); last-arriving block (ticket) does the final
// reduce + layer-2 closed-form softmax + output. Fixed-order sum -> deterministic.
__global__ __launch_bounds__(256) void k4_final(const float* __restrict__ Wout,
                                                const float* __restrict__ aout,
                                                const float* __restrict__ V,
                                                float* __restrict__ wsf,
                                                float* __restrict__ out) {
  __shared__ __align__(16) float midT[3072];
  __shared__ float whp4[4][768];
  __shared__ float Wh2[768];
  __shared__ float e1o[12], e2o[12], mr[12], sr[12], avals[12];
  __shared__ int lastflag;
  int b = blockIdx.x, t = threadIdx.x, l = t & 63, w = t >> 6;
  int* ip = (int*)(wsf + INT_OFF);
  int M = ip[H_M], R = ip[H_R];

  #pragma unroll
  for (int m = 0; m < 12; ++m) {
    float v = 0.f;
    if (m < R) v = wsf[MIDC_OFF + m * 32768 + b * 256 + t];
    midT[t * 12 + m] = v;
  }
  __syncthreads();
  float acc[12];
  #pragma unroll
  for (int m = 0; m < 12; ++m) acc[m] = 0.f;
  #pragma unroll 2
  for (int ci = 0; ci < 64; ++ci) {
    int cc = w * 64 + ci;
    float wv = Wout[(b * 256 + cc) * 64 + l];
    const float4* xr = reinterpret_cast<const float4*>(&midT[cc * 12]);
    float4 xa = xr[0], xb = xr[1], xc = xr[2];
    acc[0] += xa.x * wv; acc[1] += xa.y * wv; acc[2]  += xa.z * wv; acc[3]  += xa.w * wv;
    acc[4] += xb.x * wv; acc[5] += xb.y * wv; acc[6]  += xb.z * wv; acc[7]  += xb.w * wv;
    acc[8] += xc.x * wv; acc[9] += xc.y * wv; acc[10] += xc.z * wv; acc[11] += xc.w * wv;
  }
  #pragma unroll
  for (int m = 0; m < 12; ++m) whp4[w][m * 64 + l] = acc[m];
  __syncthreads();
  #pragma unroll
  for (int c = 0; c < 3; ++c) {
    int o = c * 256 + t;
    float s = whp4[0][o] + whp4[1][o] + whp4[2][o] + whp4[3][o];
    wsf[PART_OFF + b * 768 + o] = s;
  }

  // ---- ticket: last block of 128 performs the finale ----
  __threadfence();
  __syncthreads();
  if (t == 0) {
    int old = atomicAdd(&ip[H_TICKET], 1);
    lastflag = (old == 127) ? 1 : 0;
  }
  __syncthreads();
  if (!lastflag) return;
  __threadfence();   // acquire: invalidate stale L2 lines before reading partials

  for (int o = t, c = 0; c < 3; ++c, o += 256) {
    float s = 0.f;
    #pragma unroll 8
    for (int bb = 0; bb < 128; ++bb) s += wsf[PART_OFF + bb * 768 + o];
    Wh2[o] = s;
  }
  __syncthreads();
  if (t < R) {
    float s1 = 0.f, s2 = 0.f;
    for (int k = 0; k < 64; ++k) {
      float wv = Wh2[t * 64 + k];
      s1 += wv * aout[k];
      s2 += wv * aout[64 + k];
    }
    e1o[t] = s1; e2o[t] = s2;
  }
  __syncthreads();
  if (t < R) {
    float maxe = 0.f;  // includes (512-R) implicit zeros
    for (int r = 0; r < R; ++r) maxe = fmaxf(maxe, e2o[r]);
    float m_ = leaky_(e1o[t] + maxe);
    float s = (float)(512 - R) * __expf(leaky_(e1o[t]) - m_);
    for (int r = 0; r < R; ++r) s += __expf(leaky_(e1o[t] + e2o[r]) - m_);
    mr[t] = m_; sr[t] = s;
  }
  __syncthreads();
  if (t < M) {
    int r = ip[H_ER + t];
    int cj = ip[H_ECJ + t];
    float e2v = (cj >= 0) ? e2o[cj] : 0.f;
    avals[t] = __expf(leaky_(e1o[r] + e2v) - mr[r]) / sr[r];
  }
  __syncthreads();
  for (int r = w; r < R; r += 4) {
    float a = 0.f;
    #pragma unroll
    for (int m = 0; m < 12; ++m) {
      if (m < M && ip[H_ER + m] == r) {
        int cj = ip[H_ECJ + m];
        float wv = (cj >= 0) ? Wh2[cj * 64 + l] : 0.f;
        a += avals[m] * wv;
      }
    }
    int row = ip[H_ROWS + r];
    float o2 = elu_(a);
    out[262144 + row * 64 + l] = elu_(V[row * 64 + l] * o2);
  }
}

extern "C" void kernel_launch(void* const* d_in, const int* in_sizes, int n_in,
                              void* d_out, int out_size, void* d_ws, size_t ws_size,
                              hipStream_t stream) {
  const float* X    = (const float*)d_in[0];
  const float* Wst  = (const float*)d_in[1];
  const float* ast  = (const float*)d_in[2];
  const float* Wout = (const float*)d_in[3];
  const float* aout = (const float*)d_in[4];
  const float* V    = (const float*)d_in[5];
  float* out = (float*)d_out;
  float* wsf = (float*)d_ws;

  k1_prep  <<<1056, 256, 0, stream>>>(V, X, Wst, ast, wsf, out);
  k2_e2hdr <<<257,  256, 0, stream>>>(X, wsf);
  k3_heads <<<512,  256, 0, stream>>>(X, Wst, wsf, out);
  k4_final <<<128,  256, 0, stream>>>(Wout, aout, V, wsf, out);
}

// Round 7
// 135.789 us; speedup vs baseline: 2.8710x; 1.0359x over previous
//
#include <hip/hip_runtime.h>

// ---------------- problem constants ----------------
// N=512 nodes/heads, F_IN=256, H=64, C=64, K=12, ALPHA=0.2
// d_out: adj (512x512) followed by out (512x64), float32

// ---------------- ws float offsets ----------------
#define CAND_OFF 0        // 512*12 float2 = 12288 floats
#define XT_OFF   12288    // 131072 : X^T [256][512]
#define KTH_OFF  143360   // 1 (padded to 64)
#define INT_OFF  143424   // 64 int slots (header + ticket)
#define W1_OFF   143488   // 512*256 : w1[h][f]
#define W2_OFF   274560   // 512*256 : w2[h][f]
#define E2P_OFF  405632   // 4*512*512 : E2 f-quarter partials [q][h][j]
#define MIDC_OFF 1454208  // 12*32768 : compact mid rows
#define PART_OFF 1847424  // 128*768  : Wh2 partials [block][o]

// header int indices
#define H_M      0
#define H_R      1
#define H_ROWS   2
#define H_ER     14
#define H_EJ     26
#define H_ECJ    38
#define H_TICKET 60

__device__ __forceinline__ float leaky_(float x) { return fmaxf(x, 0.2f * x); }
__device__ __forceinline__ float elu_(float x)   { return x > 0.f ? x : __expf(x) - 1.f; }

// K1: blocks 0..511: A row b = V[b]·V^T + per-row top-12 (wave-local, 1 barrier)
//     blocks 512..543: X^T tile transpose
//     blocks 544..1055: w1/w2 for head (b-544) — W_stack streamed, deferred reduce
__global__ __launch_bounds__(256) void k1_prep(const float* __restrict__ V,
                                               const float* __restrict__ X,
                                               const float* __restrict__ Wst,
                                               const float* __restrict__ ast,
                                               float* __restrict__ wsf,
                                               float* __restrict__ out) {
  __shared__ float vi[64];
  __shared__ float wv[48]; __shared__ int wi[48];
  __shared__ float tile[64][65];
  int b = blockIdx.x, t = threadIdx.x, l = t & 63, w = t >> 6;

  if (b < 512) {
    if (b == 0 && t == 0) ((int*)(wsf + INT_OFF))[H_TICKET] = 0;  // reset k4 ticket each call
    if (t < 64) vi[t] = V[b * 64 + t];
    __syncthreads();
    float vr0, vr1;
    {
      const float4* vj = reinterpret_cast<const float4*>(V + t * 64);
      float acc = 0.f;
      #pragma unroll
      for (int q = 0; q < 16; ++q) {
        float4 v4 = vj[q];
        acc += v4.x * vi[q*4] + v4.y * vi[q*4+1] + v4.z * vi[q*4+2] + v4.w * vi[q*4+3];
      }
      vr0 = acc;
    }
    {
      const float4* vj = reinterpret_cast<const float4*>(V + (t + 256) * 64);
      float acc = 0.f;
      #pragma unroll
      for (int q = 0; q < 16; ++q) {
        float4 v4 = vj[q];
        acc += v4.x * vi[q*4] + v4.y * vi[q*4+1] + v4.z * vi[q*4+2] + v4.w * vi[q*4+3];
      }
      vr1 = acc;
    }
    out[b * 512 + t]       = vr0;
    out[b * 512 + 256 + t] = vr1;
    if (b < 128) out[262144 + b * 256 + t] = 0.f;

    // wave-local top-12 (no barriers inside rounds)
    float v0 = vr0, v1 = vr1;
    int j0 = t, j1 = t + 256;
    for (int round = 0; round < 12; ++round) {
      float m; int mi;
      if (v0 >= v1) { m = v0; mi = j0; } else { m = v1; mi = j1; }
      #pragma unroll
      for (int d = 1; d < 64; d <<= 1) {
        float ov = __shfl_xor(m, d);
        int   oi = __shfl_xor(mi, d);
        if (ov > m || (ov == m && oi < mi)) { m = ov; mi = oi; }
      }
      if (l == 0) { wv[w * 12 + round] = m; wi[w * 12 + round] = mi; }
      if (mi == j0) v0 = -INFINITY;
      if (mi == j1) v1 = -INFINITY;
    }
    __syncthreads();
    if (w == 0) {
      float cv = (l < 48) ? wv[l] : -INFINITY;
      int   ci = (l < 48) ? wi[l] : 0x7FFFFFFF;
      for (int round = 0; round < 12; ++round) {
        float m = cv; int mi = ci;
        #pragma unroll
        for (int d = 1; d < 64; d <<= 1) {
          float ov = __shfl_xor(m, d);
          int   oi = __shfl_xor(mi, d);
          if (ov > m || (ov == m && oi < mi)) { m = ov; mi = oi; }
        }
        if (l == 0) {
          float2 c; c.x = m; c.y = __int_as_float(b * 512 + mi);
          *reinterpret_cast<float2*>(wsf + CAND_OFF + (b * 12 + round) * 2) = c;
        }
        if (ci == mi) cv = -INFINITY;   // indices unique within block
      }
    }
  } else if (b < 544) {
    int ti = b - 512;
    int tjj = ti & 7, tff = ti >> 3;
    int r = t >> 2, c0 = (t & 3) * 16;
    #pragma unroll
    for (int u = 0; u < 4; ++u) {
      float4 x4 = *reinterpret_cast<const float4*>(X + (tjj*64 + r)*256 + tff*64 + c0 + u*4);
      tile[c0+u*4+0][r] = x4.x; tile[c0+u*4+1][r] = x4.y;
      tile[c0+u*4+2][r] = x4.z; tile[c0+u*4+3][r] = x4.w;
    }
    __syncthreads();
    int fl = t >> 2, jc0 = (t & 3) * 16;
    #pragma unroll
    for (int u = 0; u < 4; ++u) {
      float4 o4 = make_float4(tile[fl][jc0+u*4+0], tile[fl][jc0+u*4+1],
                              tile[fl][jc0+u*4+2], tile[fl][jc0+u*4+3]);
      *reinterpret_cast<float4*>(wsf + XT_OFF + (tff*64 + fl)*512 + tjj*64 + jc0 + u*4) = o4;
    }
  } else {
    // w1/w2 pass: head h, pure stream of W_h with deferred 16-lane reduction
    int h = b - 544;
    int kc = (t & 15) << 2;
    float4 a1q = *reinterpret_cast<const float4*>(ast + h * 128 + kc);
    float4 a2q = *reinterpret_cast<const float4*>(ast + h * 128 + 64 + kc);
    const float* Wb = Wst + h * 16384;
    float p1a[16], p2a[16];
    #pragma unroll
    for (int it = 0; it < 16; ++it) {
      float4 wq = *reinterpret_cast<const float4*>(Wb + it * 1024 + t * 4);
      p1a[it] = wq.x*a1q.x + wq.y*a1q.y + wq.z*a1q.z + wq.w*a1q.w;
      p2a[it] = wq.x*a2q.x + wq.y*a2q.y + wq.z*a2q.z + wq.w*a2q.w;
    }
    #pragma unroll
    for (int it = 0; it < 16; ++it) {
      float p1 = p1a[it], p2 = p2a[it];
      #pragma unroll
      for (int d = 1; d < 16; d <<= 1) { p1 += __shfl_xor(p1, d); p2 += __shfl_xor(p2, d); }
      if ((t & 15) == 0) {
        int f = it * 16 + (t >> 4);
        wsf[W1_OFF + h * 256 + f] = p1;
        wsf[W2_OFF + h * 256 + f] = p2;
      }
    }
  }
}

// K2: blocks 0..255: E2 f-quarter-partial GEMM (W2 · X^T).
//     block 256: header build from 6144 candidates (register-resident, ballot).
__global__ __launch_bounds__(256) void k2_e2hdr(const float* __restrict__ X,
                                                float* __restrict__ wsf) {
  __shared__ __align__(16) float As[64][68];
  __shared__ __align__(16) float Bs[64][68];
  __shared__ float redv[4]; __shared__ int redi[4];
  __shared__ float candv[12]; __shared__ int candi[12];
  __shared__ int es_s[12], rows_s[12];
  __shared__ int M_s, R_s;
  int b = blockIdx.x, t = threadIdx.x, l = t & 63, w = t >> 6;

  if (b < 256) {
    int q = b >> 6, bh = (b >> 3) & 7, bj = b & 7;
    int r = t >> 2, c0 = (t & 3) * 16;
    const float* wsrc = wsf + W2_OFF + (bh * 64 + r) * 256 + q * 64 + c0;
    const float* xsrc = X + (bj * 64 + r) * 256 + q * 64 + c0;
    #pragma unroll
    for (int u = 0; u < 4; ++u) {
      float4 a4 = *reinterpret_cast<const float4*>(wsrc + u * 4);
      float4 b4 = *reinterpret_cast<const float4*>(xsrc + u * 4);
      As[c0 + u*4 + 0][r] = a4.x; As[c0 + u*4 + 1][r] = a4.y;
      As[c0 + u*4 + 2][r] = a4.z; As[c0 + u*4 + 3][r] = a4.w;
      Bs[c0 + u*4 + 0][r] = b4.x; Bs[c0 + u*4 + 1][r] = b4.y;
      Bs[c0 + u*4 + 2][r] = b4.z; Bs[c0 + u*4 + 3][r] = b4.w;
    }
    __syncthreads();
    int th = t >> 4, tj = t & 15;
    float acc[4][4] = {};
    #pragma unroll 8
    for (int f = 0; f < 64; ++f) {
      float4 a4 = *reinterpret_cast<const float4*>(&As[f][th * 4]);
      float4 b4 = *reinterpret_cast<const float4*>(&Bs[f][tj * 4]);
      float av[4] = { a4.x, a4.y, a4.z, a4.w };
      float bv[4] = { b4.x, b4.y, b4.z, b4.w };
      #pragma unroll
      for (int i = 0; i < 4; ++i)
        #pragma unroll
        for (int j = 0; j < 4; ++j)
          acc[i][j] += av[i] * bv[j];
    }
    float* dst = wsf + E2P_OFF + q * 262144 + (bh * 64 + th * 4) * 512 + bj * 64 + tj * 4;
    #pragma unroll
    for (int i = 0; i < 4; ++i) {
      float4 o4 = make_float4(acc[i][0], acc[i][1], acc[i][2], acc[i][3]);
      *reinterpret_cast<float4*>(dst + i * 512) = o4;
    }
    return;
  }

  // ---- header block ----
  float v[24]; int ix[24];
  const float2* cp = reinterpret_cast<const float2*>(wsf + CAND_OFF);
  #pragma unroll
  for (int k = 0; k < 24; ++k) {
    float2 c = cp[k * 256 + t];
    v[k] = c.x; ix[k] = __float_as_int(c.y);
  }
  unsigned rm = 0;
  for (int round = 0; round < 12; ++round) {
    float m = -INFINITY; int mi = 0x7FFFFFFF; int sel = -1;
    #pragma unroll
    for (int k = 0; k < 24; ++k) {
      bool ok = ((rm >> k) & 1u) == 0u;
      bool better = ok && (v[k] > m || (v[k] == m && ix[k] < mi));
      if (better) { m = v[k]; mi = ix[k]; sel = k; }
    }
    int lmi = mi;
    #pragma unroll
    for (int d = 1; d < 64; d <<= 1) {
      float ov = __shfl_xor(m, d);
      int   oi = __shfl_xor(mi, d);
      if (ov > m || (ov == m && oi < mi)) { m = ov; mi = oi; }
    }
    if (l == 0) { redv[w] = m; redi[w] = mi; }
    __syncthreads();
    float bm = redv[0]; int bi = redi[0];
    #pragma unroll
    for (int ww = 1; ww < 4; ++ww)
      if (redv[ww] > bm || (redv[ww] == bm && redi[ww] < bi)) { bm = redv[ww]; bi = redi[ww]; }
    if (t == 0) { candv[round] = bm; candi[round] = bi; }
    if (sel >= 0 && lmi == bi) rm |= 1u << sel;
    __syncthreads();
  }
  float kv = candv[11];
  bool valid = (t < 12) && (candv[t] > kv);
  int myidx = valid ? candi[t] : 0x7FFFFFFF;
  unsigned long long vm = __ballot(valid);
  if (t < 12) {
    int rank = 0;
    #pragma unroll
    for (int q = 0; q < 12; ++q)
      if (((vm >> q) & 1ull) && candi[q] < myidx) ++rank;
    if (valid) es_s[rank] = myidx;
    if (t == 0) M_s = (int)__popcll(vm & 0xFFFull);
  }
  __syncthreads();
  int M = M_s;
  bool isent = (t < M);
  int i2 = isent ? (es_s[t] >> 9) : -1;
  int j2 = isent ? (es_s[t] & 511) : 0;
  bool isnew = isent && (t == 0 || (es_s[t - 1] >> 9) != i2);
  unsigned long long nm = __ballot(isnew);
  if (isnew) {
    int r = (int)__popcll(nm & ((1ull << t) - 1ull));
    rows_s[r] = i2;
  }
  if (t == 0) R_s = (int)__popcll(nm & 0xFFFull);
  __syncthreads();
  int R = R_s;
  int* ip = (int*)(wsf + INT_OFF);
  if (t == 0) { ip[H_M] = M; ip[H_R] = R; wsf[KTH_OFF] = kv; }
  if (t < 12) {
    ip[H_ROWS + t] = (t < R) ? rows_s[t] : 0;
    int er = 0, ecj = -1;
    if (isent) {
      er = (int)__popcll(nm & ((2ull << t) - 1ull)) - 1;
      for (int r = 0; r < R; ++r) if (rows_s[r] == j2) ecj = r;
    }
    ip[H_ER + t]  = er;
    ip[H_EJ + t]  = isent ? j2 : 0;
    ip[H_ECJ + t] = ecj;
  }
}

// K3: one block per head. adj row write; dense W pass (Wh@entries only, no
// cross-lane ops in hot loop); e1 via precomputed w1; E2 row merge; stats; mid.
__global__ __launch_bounds__(256) void k3_heads(
    const float* __restrict__ X, const float* __restrict__ Wst,
    float* __restrict__ wsf, float* __restrict__ out) {
  __shared__ int   shdr[64];
  __shared__ __align__(16) float XeT[3072];
  __shared__ __align__(16) float whp[3072];
  __shared__ float w1l[256];
  __shared__ float e2s[512];
  __shared__ float whl[768];
  __shared__ float e1r[12], mr12[12], sr12[12], av12[12];
  __shared__ float redv[4], redf[48];

  int b = blockIdx.x, t = threadIdx.x, l = t & 63, w = t >> 6;
  const int* ip = (const int*)(wsf + INT_OFF);

  // adj row write
  {
    float kv = wsf[KTH_OFF];
    float a0 = out[b * 512 + t], a1 = out[b * 512 + 256 + t];
    out[b * 512 + t]       = (a0 > kv) ? 1.f : 0.f;
    out[b * 512 + 256 + t] = (a1 > kv) ? 1.f : 0.f;
  }
  if (t < 50) shdr[t] = ip[t];
  w1l[t] = wsf[W1_OFF + b * 256 + t];
  {
    float s0 = 0.f, s1 = 0.f;
    #pragma unroll
    for (int q = 0; q < 4; ++q) {
      s0 += wsf[E2P_OFF + q * 262144 + b * 512 + t];
      s1 += wsf[E2P_OFF + q * 262144 + b * 512 + 256 + t];
    }
    e2s[t] = s0; e2s[t + 256] = s1;
  }
  __syncthreads();
  int M = shdr[H_M], R = shdr[H_R];

  #pragma unroll
  for (int m = 0; m < 12; ++m) {
    float v = 0.f;
    if (m < M) v = X[shdr[H_EJ + m] * 256 + t];
    XeT[t * 12 + m] = v;
  }
  __syncthreads();

  // W pass: pure load+FMA (48 FMA per float4), accumulate Wh@entries
  const float* Wb = Wst + b * 16384;
  int fg = l >> 4, kc = (l & 15) << 2;
  float wh[12][4];
  #pragma unroll
  for (int m = 0; m < 12; ++m) { wh[m][0] = wh[m][1] = wh[m][2] = wh[m][3] = 0.f; }
  #pragma unroll 4
  for (int it = 0; it < 16; ++it) {
    int f = w * 64 + it * 4 + fg;
    float4 wq = *reinterpret_cast<const float4*>(Wb + f * 64 + kc);
    const float4* xr = reinterpret_cast<const float4*>(&XeT[f * 12]);
    float4 xa = xr[0], xb = xr[1], xc = xr[2];
    float xv[12] = { xa.x, xa.y, xa.z, xa.w, xb.x, xb.y, xb.z, xb.w,
                     xc.x, xc.y, xc.z, xc.w };
    #pragma unroll
    for (int m = 0; m < 12; ++m) {
      wh[m][0] += xv[m] * wq.x;
      wh[m][1] += xv[m] * wq.y;
      wh[m][2] += xv[m] * wq.z;
      wh[m][3] += xv[m] * wq.w;
    }
  }
  #pragma unroll
  for (int m = 0; m < 12; ++m) {
    #pragma unroll
    for (int q = 0; q < 4; ++q) {
      float x = wh[m][q];
      x += __shfl_xor(x, 16);
      x += __shfl_xor(x, 32);
      wh[m][q] = x;
    }
  }
  if (l < 16) {
    #pragma unroll
    for (int m = 0; m < 12; ++m) {
      float4 vv = make_float4(wh[m][0], wh[m][1], wh[m][2], wh[m][3]);
      *reinterpret_cast<float4*>(&whp[w * 768 + m * 64 + kc]) = vv;
    }
  }
  __syncthreads();
  #pragma unroll
  for (int c = 0; c < 3; ++c) {
    int o = c * 256 + t;
    whl[o] = whp[o] + whp[768 + o] + whp[1536 + o] + whp[2304 + o];
  }
  // e1 at adjacency rows (w1 precomputed in k1)
  for (int r = w; r < R; r += 4) {
    int row = shdr[H_ROWS + r];
    float p = 0.f;
    #pragma unroll
    for (int s = 0; s < 4; ++s) {
      int f = s * 64 + l;
      p += X[row * 256 + f] * w1l[f];
    }
    #pragma unroll
    for (int d = 1; d < 64; d <<= 1) p += __shfl_xor(p, d);
    if (l == 0) e1r[r] = p;
  }
  __syncthreads();

  // softmax stats
  {
    float p = fmaxf(e2s[w * 128 + l], e2s[w * 128 + 64 + l]);
    #pragma unroll
    for (int d = 1; d < 64; d <<= 1) p = fmaxf(p, __shfl_xor(p, d));
    if (l == 0) redv[w] = p;
  }
  __syncthreads();
  float maxe2 = fmaxf(fmaxf(redv[0], redv[1]), fmaxf(redv[2], redv[3]));
  for (int r = 0; r < R; ++r) {
    float e1_ = e1r[r];
    float m_ = leaky_(e1_ + maxe2);
    float pe = __expf(leaky_(e1_ + e2s[t]) - m_) + __expf(leaky_(e1_ + e2s[t + 256]) - m_);
    #pragma unroll
    for (int d = 1; d < 64; d <<= 1) pe += __shfl_xor(pe, d);
    if (l == 0) redf[r * 4 + w] = pe;
    if (t == r) mr12[r] = m_;
  }
  __syncthreads();
  if (t < R) sr12[t] = redf[t * 4] + redf[t * 4 + 1] + redf[t * 4 + 2] + redf[t * 4 + 3];
  __syncthreads();
  if (t < M) {
    int r = shdr[H_ER + t];
    av12[t] = __expf(leaky_(e1r[r] + e2s[shdr[H_EJ + t]]) - mr12[r]) / sr12[r];
  }
  __syncthreads();
  for (int r = w; r < R; r += 4) {
    float a = 0.f;
    #pragma unroll
    for (int m = 0; m < 12; ++m) {
      if (m < M && shdr[H_ER + m] == r) a += av12[m] * whl[m * 64 + l];
    }
    wsf[MIDC_OFF + r * 32768 + b * 64 + l] = elu_(a);
  }
}

// K4: Wh2 partials (128 blocks); last-arriving block (ticket) does the final
// reduce + layer-2 closed-form softmax + output. Fixed-order sum -> deterministic.
// Fences are SINGLE-LANE: __syncthreads drains each wave's stores to the XCD L2,
// so one t0 __threadfence (L2 writeback) releases the whole block's partials.
__global__ __launch_bounds__(256) void k4_final(const float* __restrict__ Wout,
                                                const float* __restrict__ aout,
                                                const float* __restrict__ V,
                                                float* __restrict__ wsf,
                                                float* __restrict__ out) {
  __shared__ __align__(16) float midT[3072];
  __shared__ float whp4[4][768];
  __shared__ float Wh2[768];
  __shared__ float e1o[12], e2o[12], mr[12], sr[12], avals[12];
  __shared__ int lastflag;
  int b = blockIdx.x, t = threadIdx.x, l = t & 63, w = t >> 6;
  int* ip = (int*)(wsf + INT_OFF);
  int M = ip[H_M], R = ip[H_R];

  #pragma unroll
  for (int m = 0; m < 12; ++m) {
    float v = 0.f;
    if (m < R) v = wsf[MIDC_OFF + m * 32768 + b * 256 + t];
    midT[t * 12 + m] = v;
  }
  __syncthreads();
  float acc[12];
  #pragma unroll
  for (int m = 0; m < 12; ++m) acc[m] = 0.f;
  #pragma unroll 2
  for (int ci = 0; ci < 64; ++ci) {
    int cc = w * 64 + ci;
    float wv = Wout[(b * 256 + cc) * 64 + l];
    const float4* xr = reinterpret_cast<const float4*>(&midT[cc * 12]);
    float4 xa = xr[0], xb = xr[1], xc = xr[2];
    acc[0] += xa.x * wv; acc[1] += xa.y * wv; acc[2]  += xa.z * wv; acc[3]  += xa.w * wv;
    acc[4] += xb.x * wv; acc[5] += xb.y * wv; acc[6]  += xb.z * wv; acc[7]  += xb.w * wv;
    acc[8] += xc.x * wv; acc[9] += xc.y * wv; acc[10] += xc.z * wv; acc[11] += xc.w * wv;
  }
  #pragma unroll
  for (int m = 0; m < 12; ++m) whp4[w][m * 64 + l] = acc[m];
  __syncthreads();
  #pragma unroll
  for (int c = 0; c < 3; ++c) {
    int o = c * 256 + t;
    float s = whp4[0][o] + whp4[1][o] + whp4[2][o] + whp4[3][o];
    wsf[PART_OFF + b * 768 + o] = s;
  }

  // ---- ticket: single-lane release fence + atomic; last block runs finale ----
  __syncthreads();                         // drains all waves' stores to L2
  if (t == 0) {
    __threadfence();                       // ONE L2 writeback for the block
    int old = atomicAdd(&ip[H_TICKET], 1);
    lastflag = (old == 127) ? 1 : 0;
  }
  __syncthreads();
  if (!lastflag) return;
  if (t == 0) __threadfence();             // ONE acquire invalidate
  __syncthreads();

  for (int o = t, c = 0; c < 3; ++c, o += 256) {
    float s = 0.f;
    #pragma unroll 8
    for (int bb = 0; bb < 128; ++bb) s += wsf[PART_OFF + bb * 768 + o];
    Wh2[o] = s;
  }
  __syncthreads();
  if (t < R) {
    float s1 = 0.f, s2 = 0.f;
    for (int k = 0; k < 64; ++k) {
      float wv = Wh2[t * 64 + k];
      s1 += wv * aout[k];
      s2 += wv * aout[64 + k];
    }
    e1o[t] = s1; e2o[t] = s2;
  }
  __syncthreads();
  if (t < R) {
    float maxe = 0.f;  // includes (512-R) implicit zeros
    for (int r = 0; r < R; ++r) maxe = fmaxf(maxe, e2o[r]);
    float m_ = leaky_(e1o[t] + maxe);
    float s = (float)(512 - R) * __expf(leaky_(e1o[t]) - m_);
    for (int r = 0; r < R; ++r) s += __expf(leaky_(e1o[t] + e2o[r]) - m_);
    mr[t] = m_; sr[t] = s;
  }
  __syncthreads();
  if (t < M) {
    int r = ip[H_ER + t];
    int cj = ip[H_ECJ + t];
    float e2v = (cj >= 0) ? e2o[cj] : 0.f;
    avals[t] = __expf(leaky_(e1o[r] + e2v) - mr[r]) / sr[r];
  }
  __syncthreads();
  for (int r = w; r < R; r += 4) {
    float a = 0.f;
    #pragma unroll
    for (int m = 0; m < 12; ++m) {
      if (m < M && ip[H_ER + m] == r) {
        int cj = ip[H_ECJ + m];
        float wv = (cj >= 0) ? Wh2[cj * 64 + l] : 0.f;
        a += avals[m] * wv;
      }
    }
    int row = ip[H_ROWS + r];
    float o2 = elu_(a);
    out[262144 + row * 64 + l] = elu_(V[row * 64 + l] * o2);
  }
}

extern "C" void kernel_launch(void* const* d_in, const int* in_sizes, int n_in,
                              void* d_out, int out_size, void* d_ws, size_t ws_size,
                              hipStream_t stream) {
  const float* X    = (const float*)d_in[0];
  const float* Wst  = (const float*)d_in[1];
  const float* ast  = (const float*)d_in[2];
  const float* Wout = (const float*)d_in[3];
  const float* aout = (const float*)d_in[4];
  const float* V    = (const float*)d_in[5];
  float* out = (float*)d_out;
  float* wsf = (float*)d_ws;

  k1_prep  <<<1056, 256, 0, stream>>>(V, X, Wst, ast, wsf, out);
  k2_e2hdr <<<257,  256, 0, stream>>>(X, wsf);
  k3_heads <<<512,  256, 0, stream>>>(X, Wst, wsf, out);
  k4_final <<<128,  256, 0, stream>>>(Wout, aout, V, wsf, out);
}

// Round 8
// 132.766 us; speedup vs baseline: 2.9363x; 1.0228x over previous
//
#include <hip/hip_runtime.h>

// ---------------- problem constants ----------------
// N=512 nodes/heads, F_IN=256, H=64, C=64, K=12, ALPHA=0.2
// d_out: adj (512x512) followed by out (512x64), float32

// ---------------- ws float offsets ----------------
#define CAND_OFF 0        // 512*12 float2 = 12288 floats
#define XT_OFF   12288    // 131072 : X^T [256][512]
#define KTH_OFF  143360   // 1 (padded to 64)
#define INT_OFF  143424   // 64 int slots (header)
#define W1_OFF   143488   // 512*256 : w1[h][f]
#define W2_OFF   274560   // 512*256 : w2[h][f]
#define E2P_OFF  405632   // 4*512*512 : E2 f-quarter partials [q][h][j]
#define MIDC_OFF 1454208  // 12*32768 : compact mid rows
#define PART_OFF 1847424  // 128*768  : Wh2 partials [block][o]

// header int indices
#define H_M      0
#define H_R      1
#define H_ROWS   2
#define H_ER     14
#define H_EJ     26
#define H_ECJ    38

__device__ __forceinline__ float leaky_(float x) { return fmaxf(x, 0.2f * x); }
__device__ __forceinline__ float elu_(float x)   { return x > 0.f ? x : __expf(x) - 1.f; }

// K1: blocks 0..511: A row b = V[b]·V^T + per-row top-12 (wave-local, 1 barrier)
//     blocks 512..543: X^T tile transpose
//     blocks 544..1055: w1/w2 for head (b-544) — W_stack streamed, deferred reduce
__global__ __launch_bounds__(256) void k1_prep(const float* __restrict__ V,
                                               const float* __restrict__ X,
                                               const float* __restrict__ Wst,
                                               const float* __restrict__ ast,
                                               float* __restrict__ wsf,
                                               float* __restrict__ out) {
  __shared__ float vi[64];
  __shared__ float wv[48]; __shared__ int wi[48];
  __shared__ float tile[64][65];
  int b = blockIdx.x, t = threadIdx.x, l = t & 63, w = t >> 6;

  if (b < 512) {
    if (t < 64) vi[t] = V[b * 64 + t];
    __syncthreads();
    float vr0, vr1;
    {
      const float4* vj = reinterpret_cast<const float4*>(V + t * 64);
      float acc = 0.f;
      #pragma unroll
      for (int q = 0; q < 16; ++q) {
        float4 v4 = vj[q];
        acc += v4.x * vi[q*4] + v4.y * vi[q*4+1] + v4.z * vi[q*4+2] + v4.w * vi[q*4+3];
      }
      vr0 = acc;
    }
    {
      const float4* vj = reinterpret_cast<const float4*>(V + (t + 256) * 64);
      float acc = 0.f;
      #pragma unroll
      for (int q = 0; q < 16; ++q) {
        float4 v4 = vj[q];
        acc += v4.x * vi[q*4] + v4.y * vi[q*4+1] + v4.z * vi[q*4+2] + v4.w * vi[q*4+3];
      }
      vr1 = acc;
    }
    out[b * 512 + t]       = vr0;
    out[b * 512 + 256 + t] = vr1;
    if (b < 128) out[262144 + b * 256 + t] = 0.f;

    // wave-local top-12 (no barriers inside rounds)
    float v0 = vr0, v1 = vr1;
    int j0 = t, j1 = t + 256;
    for (int round = 0; round < 12; ++round) {
      float m; int mi;
      if (v0 >= v1) { m = v0; mi = j0; } else { m = v1; mi = j1; }
      #pragma unroll
      for (int d = 1; d < 64; d <<= 1) {
        float ov = __shfl_xor(m, d);
        int   oi = __shfl_xor(mi, d);
        if (ov > m || (ov == m && oi < mi)) { m = ov; mi = oi; }
      }
      if (l == 0) { wv[w * 12 + round] = m; wi[w * 12 + round] = mi; }
      if (mi == j0) v0 = -INFINITY;
      if (mi == j1) v1 = -INFINITY;
    }
    __syncthreads();
    if (w == 0) {
      float cv = (l < 48) ? wv[l] : -INFINITY;
      int   ci = (l < 48) ? wi[l] : 0x7FFFFFFF;
      for (int round = 0; round < 12; ++round) {
        float m = cv; int mi = ci;
        #pragma unroll
        for (int d = 1; d < 64; d <<= 1) {
          float ov = __shfl_xor(m, d);
          int   oi = __shfl_xor(mi, d);
          if (ov > m || (ov == m && oi < mi)) { m = ov; mi = oi; }
        }
        if (l == 0) {
          float2 c; c.x = m; c.y = __int_as_float(b * 512 + mi);
          *reinterpret_cast<float2*>(wsf + CAND_OFF + (b * 12 + round) * 2) = c;
        }
        if (ci == mi) cv = -INFINITY;   // indices unique within block
      }
    }
  } else if (b < 544) {
    int ti = b - 512;
    int tjj = ti & 7, tff = ti >> 3;
    int r = t >> 2, c0 = (t & 3) * 16;
    #pragma unroll
    for (int u = 0; u < 4; ++u) {
      float4 x4 = *reinterpret_cast<const float4*>(X + (tjj*64 + r)*256 + tff*64 + c0 + u*4);
      tile[c0+u*4+0][r] = x4.x; tile[c0+u*4+1][r] = x4.y;
      tile[c0+u*4+2][r] = x4.z; tile[c0+u*4+3][r] = x4.w;
    }
    __syncthreads();
    int fl = t >> 2, jc0 = (t & 3) * 16;
    #pragma unroll
    for (int u = 0; u < 4; ++u) {
      float4 o4 = make_float4(tile[fl][jc0+u*4+0], tile[fl][jc0+u*4+1],
                              tile[fl][jc0+u*4+2], tile[fl][jc0+u*4+3]);
      *reinterpret_cast<float4*>(wsf + XT_OFF + (tff*64 + fl)*512 + tjj*64 + jc0 + u*4) = o4;
    }
  } else {
    // w1/w2 pass: head h, pure stream of W_h with deferred 16-lane reduction
    int h = b - 544;
    int kc = (t & 15) << 2;
    float4 a1q = *reinterpret_cast<const float4*>(ast + h * 128 + kc);
    float4 a2q = *reinterpret_cast<const float4*>(ast + h * 128 + 64 + kc);
    const float* Wb = Wst + h * 16384;
    float p1a[16], p2a[16];
    #pragma unroll
    for (int it = 0; it < 16; ++it) {
      float4 wq = *reinterpret_cast<const float4*>(Wb + it * 1024 + t * 4);
      p1a[it] = wq.x*a1q.x + wq.y*a1q.y + wq.z*a1q.z + wq.w*a1q.w;
      p2a[it] = wq.x*a2q.x + wq.y*a2q.y + wq.z*a2q.z + wq.w*a2q.w;
    }
    #pragma unroll
    for (int it = 0; it < 16; ++it) {
      float p1 = p1a[it], p2 = p2a[it];
      #pragma unroll
      for (int d = 1; d < 16; d <<= 1) { p1 += __shfl_xor(p1, d); p2 += __shfl_xor(p2, d); }
      if ((t & 15) == 0) {
        int f = it * 16 + (t >> 4);
        wsf[W1_OFF + h * 256 + f] = p1;
        wsf[W2_OFF + h * 256 + f] = p2;
      }
    }
  }
}

// K2: blocks 0..255: E2 f-quarter-partial GEMM (W2 · X^T).
//     block 256: header build from 6144 candidates (register-resident, ballot).
__global__ __launch_bounds__(256) void k2_e2hdr(const float* __restrict__ X,
                                                float* __restrict__ wsf) {
  __shared__ __align__(16) float As[64][68];
  __shared__ __align__(16) float Bs[64][68];
  __shared__ float redv[4]; __shared__ int redi[4];
  __shared__ float candv[12]; __shared__ int candi[12];
  __shared__ int es_s[12], rows_s[12];
  __shared__ int M_s, R_s;
  int b = blockIdx.x, t = threadIdx.x, l = t & 63, w = t >> 6;

  if (b < 256) {
    int q = b >> 6, bh = (b >> 3) & 7, bj = b & 7;
    int r = t >> 2, c0 = (t & 3) * 16;
    const float* wsrc = wsf + W2_OFF + (bh * 64 + r) * 256 + q * 64 + c0;
    const float* xsrc = X + (bj * 64 + r) * 256 + q * 64 + c0;
    #pragma unroll
    for (int u = 0; u < 4; ++u) {
      float4 a4 = *reinterpret_cast<const float4*>(wsrc + u * 4);
      float4 b4 = *reinterpret_cast<const float4*>(xsrc + u * 4);
      As[c0 + u*4 + 0][r] = a4.x; As[c0 + u*4 + 1][r] = a4.y;
      As[c0 + u*4 + 2][r] = a4.z; As[c0 + u*4 + 3][r] = a4.w;
      Bs[c0 + u*4 + 0][r] = b4.x; Bs[c0 + u*4 + 1][r] = b4.y;
      Bs[c0 + u*4 + 2][r] = b4.z; Bs[c0 + u*4 + 3][r] = b4.w;
    }
    __syncthreads();
    int th = t >> 4, tj = t & 15;
    float acc[4][4] = {};
    #pragma unroll 8
    for (int f = 0; f < 64; ++f) {
      float4 a4 = *reinterpret_cast<const float4*>(&As[f][th * 4]);
      float4 b4 = *reinterpret_cast<const float4*>(&Bs[f][tj * 4]);
      float av[4] = { a4.x, a4.y, a4.z, a4.w };
      float bv[4] = { b4.x, b4.y, b4.z, b4.w };
      #pragma unroll
      for (int i = 0; i < 4; ++i)
        #pragma unroll
        for (int j = 0; j < 4; ++j)
          acc[i][j] += av[i] * bv[j];
    }
    float* dst = wsf + E2P_OFF + q * 262144 + (bh * 64 + th * 4) * 512 + bj * 64 + tj * 4;
    #pragma unroll
    for (int i = 0; i < 4; ++i) {
      float4 o4 = make_float4(acc[i][0], acc[i][1], acc[i][2], acc[i][3]);
      *reinterpret_cast<float4*>(dst + i * 512) = o4;
    }
    return;
  }

  // ---- header block ----
  float v[24]; int ix[24];
  const float2* cp = reinterpret_cast<const float2*>(wsf + CAND_OFF);
  #pragma unroll
  for (int k = 0; k < 24; ++k) {
    float2 c = cp[k * 256 + t];
    v[k] = c.x; ix[k] = __float_as_int(c.y);
  }
  unsigned rm = 0;
  for (int round = 0; round < 12; ++round) {
    float m = -INFINITY; int mi = 0x7FFFFFFF; int sel = -1;
    #pragma unroll
    for (int k = 0; k < 24; ++k) {
      bool ok = ((rm >> k) & 1u) == 0u;
      bool better = ok && (v[k] > m || (v[k] == m && ix[k] < mi));
      if (better) { m = v[k]; mi = ix[k]; sel = k; }
    }
    int lmi = mi;
    #pragma unroll
    for (int d = 1; d < 64; d <<= 1) {
      float ov = __shfl_xor(m, d);
      int   oi = __shfl_xor(mi, d);
      if (ov > m || (ov == m && oi < mi)) { m = ov; mi = oi; }
    }
    if (l == 0) { redv[w] = m; redi[w] = mi; }
    __syncthreads();
    float bm = redv[0]; int bi = redi[0];
    #pragma unroll
    for (int ww = 1; ww < 4; ++ww)
      if (redv[ww] > bm || (redv[ww] == bm && redi[ww] < bi)) { bm = redv[ww]; bi = redi[ww]; }
    if (t == 0) { candv[round] = bm; candi[round] = bi; }
    if (sel >= 0 && lmi == bi) rm |= 1u << sel;
    __syncthreads();
  }
  float kv = candv[11];
  bool valid = (t < 12) && (candv[t] > kv);
  int myidx = valid ? candi[t] : 0x7FFFFFFF;
  unsigned long long vm = __ballot(valid);
  if (t < 12) {
    int rank = 0;
    #pragma unroll
    for (int q = 0; q < 12; ++q)
      if (((vm >> q) & 1ull) && candi[q] < myidx) ++rank;
    if (valid) es_s[rank] = myidx;
    if (t == 0) M_s = (int)__popcll(vm & 0xFFFull);
  }
  __syncthreads();
  int M = M_s;
  bool isent = (t < M);
  int i2 = isent ? (es_s[t] >> 9) : -1;
  int j2 = isent ? (es_s[t] & 511) : 0;
  bool isnew = isent && (t == 0 || (es_s[t - 1] >> 9) != i2);
  unsigned long long nm = __ballot(isnew);
  if (isnew) {
    int r = (int)__popcll(nm & ((1ull << t) - 1ull));
    rows_s[r] = i2;
  }
  if (t == 0) R_s = (int)__popcll(nm & 0xFFFull);
  __syncthreads();
  int R = R_s;
  int* ip = (int*)(wsf + INT_OFF);
  if (t == 0) { ip[H_M] = M; ip[H_R] = R; wsf[KTH_OFF] = kv; }
  if (t < 12) {
    ip[H_ROWS + t] = (t < R) ? rows_s[t] : 0;
    int er = 0, ecj = -1;
    if (isent) {
      er = (int)__popcll(nm & ((2ull << t) - 1ull)) - 1;
      for (int r = 0; r < R; ++r) if (rows_s[r] == j2) ecj = r;
    }
    ip[H_ER + t]  = er;
    ip[H_EJ + t]  = isent ? j2 : 0;
    ip[H_ECJ + t] = ecj;
  }
}

// K3: one block per head. adj row write; dense W pass (Wh@entries only, no
// cross-lane ops in hot loop); e1 via precomputed w1; E2 row merge; stats; mid.
__global__ __launch_bounds__(256) void k3_heads(
    const float* __restrict__ X, const float* __restrict__ Wst,
    float* __restrict__ wsf, float* __restrict__ out) {
  __shared__ int   shdr[64];
  __shared__ __align__(16) float XeT[3072];
  __shared__ __align__(16) float whp[3072];
  __shared__ float w1l[256];
  __shared__ float e2s[512];
  __shared__ float whl[768];
  __shared__ float e1r[12], mr12[12], sr12[12], av12[12];
  __shared__ float redv[4], redf[48];

  int b = blockIdx.x, t = threadIdx.x, l = t & 63, w = t >> 6;
  const int* ip = (const int*)(wsf + INT_OFF);

  // adj row write
  {
    float kv = wsf[KTH_OFF];
    float a0 = out[b * 512 + t], a1 = out[b * 512 + 256 + t];
    out[b * 512 + t]       = (a0 > kv) ? 1.f : 0.f;
    out[b * 512 + 256 + t] = (a1 > kv) ? 1.f : 0.f;
  }
  if (t < 50) shdr[t] = ip[t];
  w1l[t] = wsf[W1_OFF + b * 256 + t];
  {
    float s0 = 0.f, s1 = 0.f;
    #pragma unroll
    for (int q = 0; q < 4; ++q) {
      s0 += wsf[E2P_OFF + q * 262144 + b * 512 + t];
      s1 += wsf[E2P_OFF + q * 262144 + b * 512 + 256 + t];
    }
    e2s[t] = s0; e2s[t + 256] = s1;
  }
  __syncthreads();
  int M = shdr[H_M], R = shdr[H_R];

  #pragma unroll
  for (int m = 0; m < 12; ++m) {
    float v = 0.f;
    if (m < M) v = X[shdr[H_EJ + m] * 256 + t];
    XeT[t * 12 + m] = v;
  }
  __syncthreads();

  // W pass: pure load+FMA (48 FMA per float4), accumulate Wh@entries
  const float* Wb = Wst + b * 16384;
  int fg = l >> 4, kc = (l & 15) << 2;
  float wh[12][4];
  #pragma unroll
  for (int m = 0; m < 12; ++m) { wh[m][0] = wh[m][1] = wh[m][2] = wh[m][3] = 0.f; }
  #pragma unroll 4
  for (int it = 0; it < 16; ++it) {
    int f = w * 64 + it * 4 + fg;
    float4 wq = *reinterpret_cast<const float4*>(Wb + f * 64 + kc);
    const float4* xr = reinterpret_cast<const float4*>(&XeT[f * 12]);
    float4 xa = xr[0], xb = xr[1], xc = xr[2];
    float xv[12] = { xa.x, xa.y, xa.z, xa.w, xb.x, xb.y, xb.z, xb.w,
                     xc.x, xc.y, xc.z, xc.w };
    #pragma unroll
    for (int m = 0; m < 12; ++m) {
      wh[m][0] += xv[m] * wq.x;
      wh[m][1] += xv[m] * wq.y;
      wh[m][2] += xv[m] * wq.z;
      wh[m][3] += xv[m] * wq.w;
    }
  }
  #pragma unroll
  for (int m = 0; m < 12; ++m) {
    #pragma unroll
    for (int q = 0; q < 4; ++q) {
      float x = wh[m][q];
      x += __shfl_xor(x, 16);
      x += __shfl_xor(x, 32);
      wh[m][q] = x;
    }
  }
  if (l < 16) {
    #pragma unroll
    for (int m = 0; m < 12; ++m) {
      float4 vv = make_float4(wh[m][0], wh[m][1], wh[m][2], wh[m][3]);
      *reinterpret_cast<float4*>(&whp[w * 768 + m * 64 + kc]) = vv;
    }
  }
  __syncthreads();
  #pragma unroll
  for (int c = 0; c < 3; ++c) {
    int o = c * 256 + t;
    whl[o] = whp[o] + whp[768 + o] + whp[1536 + o] + whp[2304 + o];
  }
  // e1 at adjacency rows (w1 precomputed in k1)
  for (int r = w; r < R; r += 4) {
    int row = shdr[H_ROWS + r];
    float p = 0.f;
    #pragma unroll
    for (int s = 0; s < 4; ++s) {
      int f = s * 64 + l;
      p += X[row * 256 + f] * w1l[f];
    }
    #pragma unroll
    for (int d = 1; d < 64; d <<= 1) p += __shfl_xor(p, d);
    if (l == 0) e1r[r] = p;
  }
  __syncthreads();

  // softmax stats
  {
    float p = fmaxf(e2s[w * 128 + l], e2s[w * 128 + 64 + l]);
    #pragma unroll
    for (int d = 1; d < 64; d <<= 1) p = fmaxf(p, __shfl_xor(p, d));
    if (l == 0) redv[w] = p;
  }
  __syncthreads();
  float maxe2 = fmaxf(fmaxf(redv[0], redv[1]), fmaxf(redv[2], redv[3]));
  for (int r = 0; r < R; ++r) {
    float e1_ = e1r[r];
    float m_ = leaky_(e1_ + maxe2);
    float pe = __expf(leaky_(e1_ + e2s[t]) - m_) + __expf(leaky_(e1_ + e2s[t + 256]) - m_);
    #pragma unroll
    for (int d = 1; d < 64; d <<= 1) pe += __shfl_xor(pe, d);
    if (l == 0) redf[r * 4 + w] = pe;
    if (t == r) mr12[r] = m_;
  }
  __syncthreads();
  if (t < R) sr12[t] = redf[t * 4] + redf[t * 4 + 1] + redf[t * 4 + 2] + redf[t * 4 + 3];
  __syncthreads();
  if (t < M) {
    int r = shdr[H_ER + t];
    av12[t] = __expf(leaky_(e1r[r] + e2s[shdr[H_EJ + t]]) - mr12[r]) / sr12[r];
  }
  __syncthreads();
  for (int r = w; r < R; r += 4) {
    float a = 0.f;
    #pragma unroll
    for (int m = 0; m < 12; ++m) {
      if (m < M && shdr[H_ER + m] == r) a += av12[m] * whl[m * 64 + l];
    }
    wsf[MIDC_OFF + r * 32768 + b * 64 + l] = elu_(a);
  }
}

// K4: Wh2 partials: block b covers mid columns [b*256, b*256+256).
// No in-kernel device-scope sync: end-of-dispatch flush publishes PART once.
__global__ __launch_bounds__(256) void k4_wh2(const float* __restrict__ Wout,
                                              float* __restrict__ wsf) {
  __shared__ __align__(16) float midT[3072];
  __shared__ float whp4[4][768];
  int b = blockIdx.x, t = threadIdx.x, l = t & 63, w = t >> 6;
  const int* ip = (const int*)(wsf + INT_OFF);
  int R = ip[H_R];

  #pragma unroll
  for (int m = 0; m < 12; ++m) {
    float v = 0.f;
    if (m < R) v = wsf[MIDC_OFF + m * 32768 + b * 256 + t];
    midT[t * 12 + m] = v;
  }
  __syncthreads();
  float acc[12];
  #pragma unroll
  for (int m = 0; m < 12; ++m) acc[m] = 0.f;
  #pragma unroll 2
  for (int ci = 0; ci < 64; ++ci) {
    int cc = w * 64 + ci;
    float wv = Wout[(b * 256 + cc) * 64 + l];
    const float4* xr = reinterpret_cast<const float4*>(&midT[cc * 12]);
    float4 xa = xr[0], xb = xr[1], xc = xr[2];
    acc[0] += xa.x * wv; acc[1] += xa.y * wv; acc[2]  += xa.z * wv; acc[3]  += xa.w * wv;
    acc[4] += xb.x * wv; acc[5] += xb.y * wv; acc[6]  += xb.z * wv; acc[7]  += xb.w * wv;
    acc[8] += xc.x * wv; acc[9] += xc.y * wv; acc[10] += xc.z * wv; acc[11] += xc.w * wv;
  }
  #pragma unroll
  for (int m = 0; m < 12; ++m) whp4[w][m * 64 + l] = acc[m];
  __syncthreads();
  #pragma unroll
  for (int c = 0; c < 3; ++c) {
    int o = c * 256 + t;
    float s = whp4[0][o] + whp4[1][o] + whp4[2][o] + whp4[3][o];
    wsf[PART_OFF + b * 768 + o] = s;
  }
}

// K5: reduce Wh2 partials; layer-2 closed-form softmax; final elu(V*elu(out2))
__global__ void k5_final(const float* __restrict__ aout, const float* __restrict__ V,
                         float* __restrict__ wsf, float* __restrict__ out) {
  __shared__ float Wh2[768];
  __shared__ float e1o[12], e2o[12], mr[12], sr[12], avals[12];
  int t = threadIdx.x;
  const int* ip = (const int*)(wsf + INT_OFF);
  int M = ip[H_M], R = ip[H_R];
  for (int o = t, c = 0; c < 3; ++c, o += 256) {
    float s = 0.f;
    #pragma unroll 8
    for (int bb = 0; bb < 128; ++bb) s += wsf[PART_OFF + bb * 768 + o];
    Wh2[o] = s;
  }
  __syncthreads();
  if (t < R) {
    float s1 = 0.f, s2 = 0.f;
    for (int k = 0; k < 64; ++k) {
      float wv = Wh2[t * 64 + k];
      s1 += wv * aout[k];
      s2 += wv * aout[64 + k];
    }
    e1o[t] = s1; e2o[t] = s2;
  }
  __syncthreads();
  if (t < R) {
    float maxe = 0.f;  // includes (512-R) implicit zeros
    for (int r = 0; r < R; ++r) maxe = fmaxf(maxe, e2o[r]);
    float m_ = leaky_(e1o[t] + maxe);
    float s = (float)(512 - R) * __expf(leaky_(e1o[t]) - m_);
    for (int r = 0; r < R; ++r) s += __expf(leaky_(e1o[t] + e2o[r]) - m_);
    mr[t] = m_; sr[t] = s;
  }
  __syncthreads();
  if (t < M) {
    int r = ip[H_ER + t];
    int cj = ip[H_ECJ + t];
    float e2v = (cj >= 0) ? e2o[cj] : 0.f;
    avals[t] = __expf(leaky_(e1o[r] + e2v) - mr[r]) / sr[r];
  }
  __syncthreads();
  int l = t & 63, w = t >> 6;
  for (int r = w; r < R; r += 4) {
    float a = 0.f;
    #pragma unroll
    for (int m = 0; m < 12; ++m) {
      if (m < M && ip[H_ER + m] == r) {
        int cj = ip[H_ECJ + m];
        float wv = (cj >= 0) ? Wh2[cj * 64 + l] : 0.f;
        a += avals[m] * wv;
      }
    }
    int row = ip[H_ROWS + r];
    float o2 = elu_(a);
    out[262144 + row * 64 + l] = elu_(V[row * 64 + l] * o2);
  }
}

extern "C" void kernel_launch(void* const* d_in, const int* in_sizes, int n_in,
                              void* d_out, int out_size, void* d_ws, size_t ws_size,
                              hipStream_t stream) {
  const float* X    = (const float*)d_in[0];
  const float* Wst  = (const float*)d_in[1];
  const float* ast  = (const float*)d_in[2];
  const float* Wout = (const float*)d_in[3];
  const float* aout = (const float*)d_in[4];
  const float* V    = (const float*)d_in[5];
  float* out = (float*)d_out;
  float* wsf = (float*)d_ws;

  k1_prep  <<<1056, 256, 0, stream>>>(V, X, Wst, ast, wsf, out);
  k2_e2hdr <<<257,  256, 0, stream>>>(X, wsf);
  k3_heads <<<512,  256, 0, stream>>>(X, Wst, wsf, out);
  k4_wh2   <<<128,  256, 0, stream>>>(Wout, wsf);
  k5_final <<<1,    256, 0, stream>>>(aout, V, wsf, out);
}